// Round 6
// baseline (28054.840 us; speedup 1.0000x reference)
//
#include <hip/hip_runtime.h>
#include <hip/hip_fp16.h>

#define B_   256
#define T_   512
#define D_   200
#define H_   320
#define L_   3
#define G3_  960
#define BH_  (B_*H_)
#define BTH_ (B_*T_*H_)

#define GR_   8              // independent groups (batch split)
#define RPG_  32             // rows (batch) per group
#define CPB_  48             // output cols per block
#define NCG_  20             // col-groups per layer (960/48)
#define SPG_  60             // blocks per group (3 layers * 20)
#define NBLK  (GR_*SPG_)     // 480
#define NTHR  256
#define KIP0  224            // layer-0 input K padded to 32-multiple
#define WSTR  648            // LDS weight row stride in f16 elems

typedef _Float16 half8 __attribute__((ext_vector_type(8)));
typedef float    f32x4 __attribute__((ext_vector_type(4)));
typedef unsigned u32x4 __attribute__((ext_vector_type(4)));

// ---- ws layout (floats) ----
#define OFF_STATE 0
#define SZ_STATE  (L_*BH_)                 // fp32 hidden state (fallback path only)
#define OFF_Z     (OFF_STATE + SZ_STATE)
#define SZ_Z      (L_*B_*G3_)
#define OFF_HN    (OFF_Z + SZ_Z)
#define SZ_HN     (L_*B_*H_)
#define OFF_STF   (OFF_HN + SZ_HN)         // f16 hidden state copy
#define SZ_STF_F  ((L_*BH_)/2)
#define OFF_BAR   (OFF_STF + SZ_STF_F)
#define GBAR_STRIDE 64                     // words per group's barrier region
#define BAR_WORDS   (GR_*GBAR_STRIDE)

__device__ __forceinline__ float sigmoidf_(float v) {
    return 1.0f / (1.0f + __expf(-v));
}

__device__ __forceinline__ float wredsum(float v) {
#pragma unroll
    for (int m = 32; m > 0; m >>= 1) v += __shfl_xor(v, m, 64);
    return v;
}

__device__ __forceinline__ half8 h8zero() {
    half8 a;
#pragma unroll
    for (int j = 0; j < 8; ++j) a[j] = (_Float16)0.f;
    return a;
}

// ---------- device-coherent (agent-scope, relaxed) accessors ----------
// Compile to global_load/store with sc0 sc1: bypass L1/L2, served at the
// device coherence point (Infinity Cache). No fences needed anywhere.
__device__ __forceinline__ unsigned ldc(const unsigned* p) {
    return __hip_atomic_load(p, __ATOMIC_RELAXED, __HIP_MEMORY_SCOPE_AGENT);
}
__device__ __forceinline__ void stc(unsigned* p, unsigned v) {
    __hip_atomic_store(p, v, __ATOMIC_RELAXED, __HIP_MEMORY_SCOPE_AGENT);
}
__device__ __forceinline__ float ldcf(const float* p) {
    unsigned u = ldc((const unsigned*)p);
    return __builtin_bit_cast(float, u);
}
__device__ __forceinline__ void stcf(float* p, float v) {
    stc((unsigned*)p, __builtin_bit_cast(unsigned, v));
}
__device__ __forceinline__ half8 ldch8(const _Float16* p) {
    const unsigned* q = (const unsigned*)p;
    u32x4 u;
    u.x = ldc(q + 0); u.y = ldc(q + 1); u.z = ldc(q + 2); u.w = ldc(q + 3);
    return __builtin_bit_cast(half8, u);
}

// ---------- fence-free group barrier ----------
// token = 1,2,3,... monotonically per barrier. After barrier #k completes,
// *cnt == k*SPG_. __syncthreads drains vmcnt (sc1 stores then globally
// visible); arrival/poll are relaxed agent atomics (coherence-point ops,
// no cache side effects).
__device__ __forceinline__ void group_barrier(unsigned* cnt, int tid, unsigned token) {
    __syncthreads();
    if (tid == 0) {
        __hip_atomic_fetch_add(cnt, 1u, __ATOMIC_RELAXED, __HIP_MEMORY_SCOPE_AGENT);
        while ((int)(__hip_atomic_load(cnt, __ATOMIC_RELAXED,
                                       __HIP_MEMORY_SCOPE_AGENT)
                     - token*(unsigned)SPG_) < 0)
            __builtin_amdgcn_s_sleep(1);
    }
    __syncthreads();
}

__device__ __forceinline__ void load_weights(int l, int colbase, int tid,
        const float* __restrict__ wih0, const float* __restrict__ wihr,
        const float* __restrict__ whh,  const float* __restrict__ rmean,
        const float* __restrict__ rvar,
        _Float16 (*w)[WSTR], float (*nrm)[KIP0])
{
    for (int e = tid; e < CPB_*WSTR; e += NTHR) ((_Float16*)w)[e] = (_Float16)0.f;
    if (l == 0) for (int e = tid; e < 2*KIP0; e += NTHR) ((float*)nrm)[e] = 0.f;
    __syncthreads();
    const int KI  = (l == 0) ? D_ : H_;
    const int KIP = (l == 0) ? KIP0 : H_;
    for (int e = tid; e < CPB_*KI; e += NTHR) {
        int c = e / KI, k = e - c*KI;
        float v = (l == 0) ? wih0[(size_t)(colbase + c)*D_ + k]
                           : wihr[((size_t)(l-1)*G3_ + colbase + c)*H_ + k];
        w[c][k] = (_Float16)v;
    }
    for (int e = tid; e < CPB_*H_; e += NTHR) {
        int c = e / H_, k = e - c*H_;
        w[c][KIP + k] = (_Float16)whh[((size_t)l*G3_ + colbase + c)*H_ + k];
    }
    if (l == 0) {
        for (int k = tid; k < D_; k += NTHR) {
            nrm[0][k] = rmean[k];
            nrm[1][k] = rsqrtf(rvar[k] + 1e-8f);
        }
    }
    __syncthreads();
}

template<int KTI, bool L0>
__device__ __forceinline__ void phase1_work(int g, int l, int t, int colbase, int tid,
        const float* __restrict__ x, const _Float16* __restrict__ stf,
        const float* __restrict__ bih, const float* __restrict__ bhh,
        float* __restrict__ zbuf, float* __restrict__ hnbuf,
        const _Float16 (*w)[WSTR], const float (*nrm)[KIP0])
{
    const int wid  = tid >> 6;       // 0 or 1 (callers gate wid<2)
    const int lane = tid & 63;
    const int nr   = lane & 15;
    const int grp  = lane >> 4;
    const int mb   = g*RPG_ + wid*16;
    constexpr int KIP = KTI * 32;

    // ---- batch-load ALL A fragments first (preserve MLP on coherent loads) ----
    half8 aI[KTI];
    if (L0) {
#pragma unroll
        for (int kt = 0; kt < KTI; ++kt) {
            const int k0 = kt*32 + grp*8;
            if (kt == KTI-1 && grp > 0) {
                aI[kt] = h8zero();
            } else {
                const float* xr = &x[((size_t)(mb + nr)*T_ + t)*D_ + k0];
                float xv[8];
                *(float4*)&xv[0] = *(const float4*)xr;
                *(float4*)&xv[4] = *(const float4*)(xr + 4);
                half8 a;
#pragma unroll
                for (int j = 0; j < 8; ++j) {
                    float nv = (xv[j] - nrm[0][k0+j]) * nrm[1][k0+j];
                    a[j] = (_Float16)fminf(fmaxf(nv, -10.f), 10.f);
                }
                aI[kt] = a;
            }
        }
    } else {
        const _Float16* src = &stf[(size_t)(l-1)*BH_ + (size_t)(mb + nr)*H_ + grp*8];
#pragma unroll
        for (int kt = 0; kt < KTI; ++kt) aI[kt] = ldch8(src + kt*32);
    }
    half8 aH[10];
    {
        const _Float16* src = &stf[(size_t)l*BH_ + (size_t)(mb + nr)*H_ + grp*8];
#pragma unroll
        for (int kt = 0; kt < 10; ++kt) aH[kt] = ldch8(src + kt*32);
    }

    f32x4 accI[3], accH[3];
#pragma unroll
    for (int nt = 0; nt < 3; ++nt) {
#pragma unroll
        for (int r = 0; r < 4; ++r) { accI[nt][r] = 0.f; accH[nt][r] = 0.f; }
    }

#pragma unroll
    for (int kt = 0; kt < KTI; ++kt) {
        const int k0 = kt*32 + grp*8;
#pragma unroll
        for (int nt = 0; nt < 3; ++nt) {
            half8 bf = *(const half8*)&w[nt*16 + nr][k0];
            accI[nt] = __builtin_amdgcn_mfma_f32_16x16x32_f16(aI[kt], bf, accI[nt], 0, 0, 0);
        }
    }
#pragma unroll
    for (int kt = 0; kt < 10; ++kt) {
        const int k0 = kt*32 + grp*8;
#pragma unroll
        for (int nt = 0; nt < 3; ++nt) {
            half8 bf = *(const half8*)&w[nt*16 + nr][KIP + k0];
            accH[nt] = __builtin_amdgcn_mfma_f32_16x16x32_f16(aH[kt], bf, accH[nt], 0, 0, 0);
        }
    }

    // ---- store pre-activations (device-coherent) ----
#pragma unroll
    for (int nt = 0; nt < 3; ++nt) {
        const int col = colbase + nt*16 + nr;
        const float bi = bih[l*G3_ + col];
        const float bh = bhh[l*G3_ + col];
        const bool ru = (colbase + nt*16) < 2*H_;
#pragma unroll
        for (int r = 0; r < 4; ++r) {
            const int m = mb + grp*4 + r;
            const size_t zi = ((size_t)l*B_ + m)*G3_ + col;
            if (ru) {
                stcf(&zbuf[zi], accI[nt][r] + accH[nt][r] + bi + bh);
            } else {
                stcf(&zbuf[zi], accI[nt][r] + bi);
                stcf(&hnbuf[((size_t)l*B_ + m)*H_ + (col - 2*H_)], accH[nt][r] + bh);
            }
        }
    }
}

__device__ __forceinline__ void phase1_dispatch(int g, int l, int t, int colbase, int tid,
        const float* x, const _Float16* stf, const float* bih, const float* bhh,
        float* zbuf, float* hnbuf, const _Float16 (*w)[WSTR], const float (*nrm)[KIP0])
{
    if ((tid >> 6) >= 2) return;   // 2 waves of 16 rows cover RPG_=32
    if (l == 0) phase1_work<7,  true >(g, l, t, colbase, tid, x, stf, bih, bhh, zbuf, hnbuf, w, nrm);
    else        phase1_work<10, false>(g, l, t, colbase, tid, x, stf, bih, bhh, zbuf, hnbuf, w, nrm);
}

// REGH=true: h kept in caller's registers (coop persistent kernel).
// REGH=false: h in fp32 state buffer (multi-launch fallback).
template<bool REGH>
__device__ __forceinline__ void phase2_work(int g, int tau, int wv, int lane,
        const float* __restrict__ lng, const float* __restrict__ lnb,
        float* __restrict__ state, float* hreg,
        _Float16* __restrict__ stf,
        const float* __restrict__ zbuf, const float* __restrict__ hnbuf,
        float* __restrict__ out)
{
    if (wv >= L_*RPG_) return;            // 96 tasks per group
    const int l2  = wv >> 5;
    const int row = wv & 31;
    const int b2  = g*RPG_ + row;
    const int t2  = tau - l2;
    if (t2 < 0 || t2 >= T_) return;

    const float* zrow  = &zbuf[((size_t)l2*B_ + b2)*G3_];
    const float* hnrow = &hnbuf[((size_t)l2*B_ + b2)*H_];
    _Float16*    frow  = &stf[(size_t)l2*BH_ + (size_t)b2*H_];

    float zr[5], zu[5], zn[5], hn[5];
#pragma unroll
    for (int i = 0; i < 5; ++i) {
        const int j = lane + i*64;
        zr[i] = ldcf(zrow + j);
        zu[i] = ldcf(zrow + 320 + j);
        zn[i] = ldcf(zrow + 640 + j);
        hn[i] = ldcf(hnrow + j);
    }
    const float inv320 = 1.0f/320.0f;
    float s  = zr[0]+zr[1]+zr[2]+zr[3]+zr[4];
    float mu = wredsum(s) * inv320;
    float vs = 0.f;
#pragma unroll
    for (int i = 0; i < 5; ++i) { float d = zr[i]-mu; vs += d*d; }
    float inv = rsqrtf(wredsum(vs)*inv320 + 1e-5f);
    float r[5];
#pragma unroll
    for (int i = 0; i < 5; ++i) {
        const int j = lane + i*64;
        r[i] = sigmoidf_((zr[i]-mu)*inv * lng[(l2*3+0)*H_ + j] + lnb[(l2*3+0)*H_ + j]);
    }
    s  = zu[0]+zu[1]+zu[2]+zu[3]+zu[4];
    mu = wredsum(s) * inv320;
    vs = 0.f;
#pragma unroll
    for (int i = 0; i < 5; ++i) { float d = zu[i]-mu; vs += d*d; }
    inv = rsqrtf(wredsum(vs)*inv320 + 1e-5f);
    float u[5];
#pragma unroll
    for (int i = 0; i < 5; ++i) {
        const int j = lane + i*64;
        u[i] = sigmoidf_((zu[i]-mu)*inv * lng[(l2*3+1)*H_ + j] + lnb[(l2*3+1)*H_ + j]);
    }
    float z2[5];
#pragma unroll
    for (int i = 0; i < 5; ++i) z2[i] = zn[i] + r[i]*hn[i];
    s  = z2[0]+z2[1]+z2[2]+z2[3]+z2[4];
    mu = wredsum(s) * inv320;
    vs = 0.f;
#pragma unroll
    for (int i = 0; i < 5; ++i) { float d = z2[i]-mu; vs += d*d; }
    inv = rsqrtf(wredsum(vs)*inv320 + 1e-5f);
#pragma unroll
    for (int i = 0; i < 5; ++i) {
        const int j = lane + i*64;
        float nv = tanhf((z2[i]-mu)*inv * lng[(l2*3+2)*H_ + j] + lnb[(l2*3+2)*H_ + j]);
        float hp;
        if constexpr (REGH) hp = hreg[i];
        else                hp = state[(size_t)l2*BH_ + (size_t)b2*H_ + j];
        float hv = (1.0f - u[i])*nv + u[i]*hp;
        if constexpr (REGH) hreg[i] = hv;
        else                state[(size_t)l2*BH_ + (size_t)b2*H_ + j] = hv;
        // f16 copy: pair up adjacent lanes into one u32 coherent store
        unsigned hb = (unsigned)__builtin_bit_cast(unsigned short, (_Float16)hv);
        unsigned ob = (unsigned)__shfl_xor((int)hb, 1, 64);
        if ((lane & 1) == 0)
            stc(&((unsigned*)frow)[j >> 1], (hb & 0xffffu) | (ob << 16));
        if (l2 == 2)    out[((size_t)b2*T_ + t2)*H_ + j] = hv;
        if (t2 == T_-1) out[(size_t)BTH_ + ((size_t)l2*B_ + b2)*H_ + j] = hv;
    }
}

// ---- init: zero barrier words, copy h0 into fp32 state (fallback) + f16 ----
__global__ void k_init(const float* __restrict__ h0, float* __restrict__ ws) {
    float*     state = ws + OFF_STATE;
    _Float16*  stf   = (_Float16*)(ws + OFF_STF);
    unsigned*  bar   = (unsigned*)(ws + OFF_BAR);
    int gt = blockIdx.x*blockDim.x + threadIdx.x;
    if (gt < BAR_WORDS) bar[gt] = 0u;
    for (int i = gt; i < L_*BH_; i += gridDim.x*blockDim.x) {
        float v = h0[i];
        state[i] = v;
        stf[i]   = (_Float16)v;
    }
}

// ======================= cooperative persistent kernel =======================
__launch_bounds__(NTHR)
__global__ void gru_coop_kernel(const float* __restrict__ x,
                                const float* __restrict__ h0,
                                const float* __restrict__ rmean,
                                const float* __restrict__ rvar,
                                const float* __restrict__ wih0,
                                const float* __restrict__ wihr,
                                const float* __restrict__ whh,
                                const float* __restrict__ bih,
                                const float* __restrict__ bhh,
                                const float* __restrict__ lng,
                                const float* __restrict__ lnb,
                                float* __restrict__ out,
                                float* __restrict__ ws)
{
    float*     zbuf  = ws + OFF_Z;
    float*     hnbuf = ws + OFF_HN;
    _Float16*  stf   = (_Float16*)(ws + OFF_STF);
    unsigned*  bar   = (unsigned*)(ws + OFF_BAR);

    const int tid = threadIdx.x;
    const int bid = blockIdx.x;
    const int g   = bid & (GR_ - 1);
    const int idx = bid >> 3;            // 0..59 within group
    const int l   = idx / NCG_;
    const int cgp = idx - l*NCG_;
    const int colbase = cgp * CPB_;

    unsigned* cnt = bar + g*GBAR_STRIDE;

    __shared__ _Float16 w_lds[CPB_][WSTR];     // 62208 B
    __shared__ float    nrm_lds[2][KIP0];      //  1792 B

    load_weights(l, colbase, tid, wih0, wihr, whh, rmean, rvar, w_lds, nrm_lds);

    const int wid  = tid >> 6;
    const int lane = tid & 63;
    const int wv   = idx*4 + wid;

    // hidden state for this wave's phase-2 task lives in registers
    float hreg[5];
    if (wv < L_*RPG_) {
        const int l2 = wv >> 5, row = wv & 31, b2 = g*RPG_ + row;
#pragma unroll
        for (int i = 0; i < 5; ++i)
            hreg[i] = h0[(size_t)l2*BH_ + (size_t)b2*H_ + lane + i*64];
    }

    for (int tau = 0; tau < T_ + L_ - 1; ++tau) {
        const int t = tau - l;
        if (t >= 0 && t < T_)
            phase1_dispatch(g, l, t, colbase, tid, x, stf, bih, bhh,
                            zbuf, hnbuf, w_lds, nrm_lds);
        group_barrier(cnt, tid, (unsigned)(2*tau + 1));
        phase2_work<true>(g, tau, wv, lane, lng, lnb, nullptr, hreg,
                          stf, zbuf, hnbuf, out);
        group_barrier(cnt, tid, (unsigned)(2*tau + 2));
    }
}

// ======================= non-cooperative fallback path =======================
__launch_bounds__(NTHR)
__global__ void k_p1(const float* __restrict__ x,
                     const float* __restrict__ rmean, const float* __restrict__ rvar,
                     const float* __restrict__ wih0,  const float* __restrict__ wihr,
                     const float* __restrict__ whh,   const float* __restrict__ bih,
                     const float* __restrict__ bhh,   float* __restrict__ ws, int tau)
{
    const int tid = threadIdx.x;
    const int bid = blockIdx.x;
    const int g   = bid & (GR_ - 1);
    const int idx = bid >> 3;
    const int l   = idx / NCG_;
    const int cgp = idx - l*NCG_;
    const int colbase = cgp * CPB_;
    const int t = tau - l;
    if (t < 0 || t >= T_) return;

    float*    zbuf  = ws + OFF_Z;
    float*    hnbuf = ws + OFF_HN;
    _Float16* stf   = (_Float16*)(ws + OFF_STF);

    __shared__ _Float16 w_lds[CPB_][WSTR];
    __shared__ float    nrm_lds[2][KIP0];
    load_weights(l, colbase, tid, wih0, wihr, whh, rmean, rvar, w_lds, nrm_lds);
    phase1_dispatch(g, l, t, colbase, tid, x, stf, bih, bhh, zbuf, hnbuf, w_lds, nrm_lds);
}

__launch_bounds__(NTHR)
__global__ void k_p2(const float* __restrict__ lng, const float* __restrict__ lnb,
                     float* __restrict__ ws, float* __restrict__ out, int tau)
{
    float*    state = ws + OFF_STATE;
    float*    zbuf  = ws + OFF_Z;
    float*    hnbuf = ws + OFF_HN;
    _Float16* stf   = (_Float16*)(ws + OFF_STF);
    const int bid = blockIdx.x;
    const int g   = bid & (GR_ - 1);
    const int idx = bid >> 3;
    phase2_work<false>(g, tau, idx*4 + (threadIdx.x >> 6), threadIdx.x & 63,
                       lng, lnb, state, nullptr, stf, zbuf, hnbuf, out);
}

extern "C" void kernel_launch(void* const* d_in, const int* in_sizes, int n_in,
                              void* d_out, int out_size, void* d_ws, size_t ws_size,
                              hipStream_t stream) {
    (void)in_sizes; (void)n_in; (void)out_size; (void)ws_size;
    const float* x     = (const float*)d_in[0];
    const float* h0    = (const float*)d_in[1];
    const float* rmean = (const float*)d_in[2];
    const float* rvar  = (const float*)d_in[3];
    const float* wih0  = (const float*)d_in[4];
    const float* wihr  = (const float*)d_in[5];
    const float* whh   = (const float*)d_in[6];
    const float* bih   = (const float*)d_in[7];
    const float* bhh   = (const float*)d_in[8];
    const float* lng   = (const float*)d_in[9];
    const float* lnb   = (const float*)d_in[10];
    float* out = (float*)d_out;
    float* ws  = (float*)d_ws;

    k_init<<<dim3(240), dim3(NTHR), 0, stream>>>(h0, ws);

    int ncu = 0, nb = 0;
    hipDeviceGetAttribute(&ncu, hipDeviceAttributeMultiprocessorCount, 0);
    hipError_t qerr = hipOccupancyMaxActiveBlocksPerMultiprocessor(
        &nb, (const void*)gru_coop_kernel, NTHR, 0);
    const bool coop_ok = (qerr == hipSuccess) && (nb > 0) &&
                         ((long long)nb * (long long)ncu >= NBLK);

    if (coop_ok) {
        void* args[13] = {
            (void*)&x, (void*)&h0, (void*)&rmean, (void*)&rvar,
            (void*)&wih0, (void*)&wihr, (void*)&whh,
            (void*)&bih, (void*)&bhh, (void*)&lng, (void*)&lnb,
            (void*)&out, (void*)&ws
        };
        hipLaunchCooperativeKernel((void*)gru_coop_kernel,
                                   dim3(NBLK), dim3(NTHR), args, 0, stream);
    } else {
        for (int tau = 0; tau < T_ + L_ - 1; ++tau) {
            k_p1<<<dim3(NBLK), dim3(NTHR), 0, stream>>>(
                x, rmean, rvar, wih0, wihr, whh, bih, bhh, ws, tau);
            k_p2<<<dim3(NBLK), dim3(NTHR), 0, stream>>>(lng, lnb, ws, out, tau);
        }
    }
}

// Round 7
// 22690.625 us; speedup vs baseline: 1.2364x; 1.2364x over previous
//
#include <hip/hip_runtime.h>
#include <hip/hip_fp16.h>
#include <hip/hip_cooperative_groups.h>

namespace cg = cooperative_groups;

#define B_   256
#define T_   512
#define D_   200
#define H_   320
#define L_   3
#define G3_  960
#define BH_  (B_*H_)
#define BTH_ (B_*T_*H_)

#define GR_   8              // groups (batch split); goal: one per XCD
#define RPG_  32             // rows (batch) per group
#define CPB_  48             // output cols per block
#define NCG_  20             // col-groups per layer (960/48)
#define SPG_  60             // blocks per group (3 layers * 20)
#define NBLK  (GR_*SPG_)     // 480 = 2 blocks/CU on 240 CUs; 60/XCD if balanced
#define NTHR  256
#define KIP0  224            // layer-0 input K padded to 32-multiple
#define WSTR  648            // LDS weight row stride in f16 elems

typedef _Float16 half8 __attribute__((ext_vector_type(8)));
typedef float    f32x4 __attribute__((ext_vector_type(4)));

// ---- ws layout (floats) ----
#define OFF_STATE 0
#define SZ_STATE  (L_*BH_)                 // fp32 hidden state (fallback path only)
#define OFF_Z     (OFF_STATE + SZ_STATE)
#define SZ_Z      (L_*B_*G3_)
#define OFF_HN    (OFF_Z + SZ_Z)
#define SZ_HN     (L_*B_*H_)
#define OFF_STF   (OFF_HN + SZ_HN)         // f16 hidden state copy
#define SZ_STF_F  ((L_*BH_)/2)
#define OFF_BAR   (OFF_STF + SZ_STF_F)
// barrier area (u32 words): det[480] @0 (pad to 512), then 8 group regions
#define FLAG_STR  16
#define EPOCH_OFF (SPG_*FLAG_STR)          // 960
#define GRP_STR   1024
#define BAR_WORDS (512 + GR_*GRP_STR)      // 8704

__device__ __forceinline__ float sigmoidf_(float v) {
    return 1.0f / (1.0f + __expf(-v));
}

__device__ __forceinline__ float wredsum(float v) {
#pragma unroll
    for (int m = 32; m > 0; m >>= 1) v += __shfl_xor(v, m, 64);
    return v;
}

__device__ __forceinline__ half8 h8zero() {
    half8 a;
#pragma unroll
    for (int j = 0; j < 8; ++j) a[j] = (_Float16)0.f;
    return a;
}

__device__ __forceinline__ unsigned aload(const unsigned* p) {
    return __hip_atomic_load(p, __ATOMIC_RELAXED, __HIP_MEMORY_SCOPE_AGENT);
}
__device__ __forceinline__ unsigned armw(unsigned* p) {
    return __hip_atomic_fetch_add(p, 0u, __ATOMIC_RELAXED, __HIP_MEMORY_SCOPE_AGENT);
}
__device__ __forceinline__ void astore(unsigned* p, unsigned v) {
    __hip_atomic_store(p, v, __ATOMIC_RELAXED, __HIP_MEMORY_SCOPE_AGENT);
}

// ---------------- group barrier ----------------
// greg: flags at [idx*FLAG_STR], epoch at [EPOCH_OFF]. token strictly increasing.
// fast (all SPG_ blocks on ONE XCD): plain stores are already in the shared L2
// (write-through vL1 + vmcnt drain in __syncthreads). Arrival = relaxed agent
// atomic flag; leader wave scans all flags in parallel; exit = vL1-only
// buffer_inv per wave. NO L2 writeback / NO L2 invalidate.
// safe (any placement): r4-proven agent fences around the same protocol.
__device__ __forceinline__ void group_barrier(unsigned* greg, int idx, int tid,
                                              unsigned token, bool fast) {
    __syncthreads();
    if (!fast && tid == 0) __threadfence();            // release (wbl2)
    if (tid == 0) astore(&greg[idx*FLAG_STR], token);
    if (idx == 0) {
        if (tid < SPG_) {                              // wave-0 lanes poll in parallel
            unsigned* f = &greg[tid*FLAG_STR];
            int spin = 0;
            for (;;) {
                unsigned v = ((++spin & 63) == 0) ? armw(f) : aload(f);
                if ((int)(v - token) >= 0) break;
                __builtin_amdgcn_s_sleep(1);
            }
        }
        // wave reconverged: all flags observed
        if (tid == 0) astore(&greg[EPOCH_OFF], token);
    } else if (tid == 0) {
        unsigned* e = &greg[EPOCH_OFF];
        int spin = 0;
        for (;;) {
            unsigned v = ((++spin & 63) == 0) ? armw(e) : aload(e);
            if ((int)(v - token) >= 0) break;
            __builtin_amdgcn_s_sleep(1);
        }
    }
    __syncthreads();
    if (fast) {
        asm volatile("buffer_inv" ::: "memory");       // vL1 only, every wave
    } else {
        if (tid == 0) __threadfence();                 // acquire (inv)
        __syncthreads();
    }
}

__device__ __forceinline__ void load_weights(int l, int colbase, int tid,
        const float* __restrict__ wih0, const float* __restrict__ wihr,
        const float* __restrict__ whh,  const float* __restrict__ rmean,
        const float* __restrict__ rvar,
        _Float16 (*w)[WSTR], float (*nrm)[KIP0])
{
    for (int e = tid; e < CPB_*WSTR; e += NTHR) ((_Float16*)w)[e] = (_Float16)0.f;
    if (l == 0) for (int e = tid; e < 2*KIP0; e += NTHR) ((float*)nrm)[e] = 0.f;
    __syncthreads();
    const int KI  = (l == 0) ? D_ : H_;
    const int KIP = (l == 0) ? KIP0 : H_;
    for (int e = tid; e < CPB_*KI; e += NTHR) {
        int c = e / KI, k = e - c*KI;
        float v = (l == 0) ? wih0[(size_t)(colbase + c)*D_ + k]
                           : wihr[((size_t)(l-1)*G3_ + colbase + c)*H_ + k];
        w[c][k] = (_Float16)v;
    }
    for (int e = tid; e < CPB_*H_; e += NTHR) {
        int c = e / H_, k = e - c*H_;
        w[c][KIP + k] = (_Float16)whh[((size_t)l*G3_ + colbase + c)*H_ + k];
    }
    if (l == 0) {
        for (int k = tid; k < D_; k += NTHR) {
            nrm[0][k] = rmean[k];
            nrm[1][k] = rsqrtf(rvar[k] + 1e-8f);
        }
    }
    __syncthreads();
}

template<int KTI, bool L0>
__device__ __forceinline__ void phase1_work(int g, int l, int t, int colbase, int tid,
        const float* __restrict__ x, const _Float16* __restrict__ stf,
        const float* __restrict__ bih, const float* __restrict__ bhh,
        float* __restrict__ zbuf, float* __restrict__ hnbuf,
        const _Float16 (*w)[WSTR], const float (*nrm)[KIP0])
{
    const int wid  = tid >> 6;       // 0 or 1 (callers gate wid<2)
    const int lane = tid & 63;
    const int nr   = lane & 15;
    const int grp  = lane >> 4;
    const int mb   = g*RPG_ + wid*16;
    constexpr int KIP = KTI * 32;

    f32x4 accI[3], accH[3];
#pragma unroll
    for (int nt = 0; nt < 3; ++nt) {
#pragma unroll
        for (int r = 0; r < 4; ++r) { accI[nt][r] = 0.f; accH[nt][r] = 0.f; }
    }

    // ---------- input-to-hidden ----------
#pragma unroll
    for (int kt = 0; kt < KTI; ++kt) {
        const int k0 = kt*32 + grp*8;
        half8 a;
        if (L0) {
            if (kt == KTI-1 && grp > 0) {
                a = h8zero();
            } else {
                const float* xr = &x[((size_t)(mb + nr)*T_ + t)*D_ + k0];
                float xv[8];
                *(float4*)&xv[0] = *(const float4*)xr;
                *(float4*)&xv[4] = *(const float4*)(xr + 4);
#pragma unroll
                for (int j = 0; j < 8; ++j) {
                    float nv = (xv[j] - nrm[0][k0+j]) * nrm[1][k0+j];
                    a[j] = (_Float16)fminf(fmaxf(nv, -10.f), 10.f);
                }
            }
        } else {
            a = *(const half8*)&stf[(size_t)(l-1)*BH_ + (size_t)(mb + nr)*H_ + k0];
        }
#pragma unroll
        for (int nt = 0; nt < 3; ++nt) {
            half8 bf = *(const half8*)&w[nt*16 + nr][k0];
            accI[nt] = __builtin_amdgcn_mfma_f32_16x16x32_f16(a, bf, accI[nt], 0, 0, 0);
        }
    }
    // ---------- hidden-to-hidden (K = 320) ----------
#pragma unroll
    for (int kt = 0; kt < 10; ++kt) {
        const int k0 = kt*32 + grp*8;
        half8 a = *(const half8*)&stf[(size_t)l*BH_ + (size_t)(mb + nr)*H_ + k0];
#pragma unroll
        for (int nt = 0; nt < 3; ++nt) {
            half8 bf = *(const half8*)&w[nt*16 + nr][KIP + k0];
            accH[nt] = __builtin_amdgcn_mfma_f32_16x16x32_f16(a, bf, accH[nt], 0, 0, 0);
        }
    }
    // ---------- store pre-activations (plain stores; write-through to L2) ----------
#pragma unroll
    for (int nt = 0; nt < 3; ++nt) {
        const int col = colbase + nt*16 + nr;
        const float bi = bih[l*G3_ + col];
        const float bh = bhh[l*G3_ + col];
        const bool ru = (colbase + nt*16) < 2*H_;
#pragma unroll
        for (int r = 0; r < 4; ++r) {
            const int m = mb + grp*4 + r;
            const size_t zi = ((size_t)l*B_ + m)*G3_ + col;
            if (ru) {
                zbuf[zi] = accI[nt][r] + accH[nt][r] + bi + bh;
            } else {
                zbuf[zi] = accI[nt][r] + bi;
                hnbuf[((size_t)l*B_ + m)*H_ + (col - 2*H_)] = accH[nt][r] + bh;
            }
        }
    }
}

__device__ __forceinline__ void phase1_dispatch(int g, int l, int t, int colbase, int tid,
        const float* x, const _Float16* stf, const float* bih, const float* bhh,
        float* zbuf, float* hnbuf, const _Float16 (*w)[WSTR], const float (*nrm)[KIP0])
{
    if ((tid >> 6) >= 2) return;   // 2 waves of 16 rows cover RPG_=32
    if (l == 0) phase1_work<7,  true >(g, l, t, colbase, tid, x, stf, bih, bhh, zbuf, hnbuf, w, nrm);
    else        phase1_work<10, false>(g, l, t, colbase, tid, x, stf, bih, bhh, zbuf, hnbuf, w, nrm);
}

// REGH=true: h in caller registers (coop kernel). false: fp32 state buffer (fallback).
template<bool REGH>
__device__ __forceinline__ void phase2_work(int g, int tau, int wv, int lane,
        const float* __restrict__ lng, const float* __restrict__ lnb,
        float* __restrict__ state, float* hreg,
        _Float16* __restrict__ stf,
        const float* __restrict__ zbuf, const float* __restrict__ hnbuf,
        float* __restrict__ out)
{
    if (wv >= L_*RPG_) return;            // 96 tasks per group
    const int l2  = wv >> 5;
    const int row = wv & 31;
    const int b2  = g*RPG_ + row;
    const int t2  = tau - l2;
    if (t2 < 0 || t2 >= T_) return;

    const float* zrow  = &zbuf[((size_t)l2*B_ + b2)*G3_];
    const float* hnrow = &hnbuf[((size_t)l2*B_ + b2)*H_];
    _Float16*    frow  = &stf[(size_t)l2*BH_ + (size_t)b2*H_];

    float zr[5], zu[5], zn[5], hn[5];
#pragma unroll
    for (int i = 0; i < 5; ++i) {
        const int j = lane + i*64;
        zr[i] = zrow[j];
        zu[i] = zrow[320 + j];
        zn[i] = zrow[640 + j];
        hn[i] = hnrow[j];
    }
    const float inv320 = 1.0f/320.0f;
    float s  = zr[0]+zr[1]+zr[2]+zr[3]+zr[4];
    float mu = wredsum(s) * inv320;
    float vs = 0.f;
#pragma unroll
    for (int i = 0; i < 5; ++i) { float d = zr[i]-mu; vs += d*d; }
    float inv = rsqrtf(wredsum(vs)*inv320 + 1e-5f);
    float r[5];
#pragma unroll
    for (int i = 0; i < 5; ++i) {
        const int j = lane + i*64;
        r[i] = sigmoidf_((zr[i]-mu)*inv * lng[(l2*3+0)*H_ + j] + lnb[(l2*3+0)*H_ + j]);
    }
    s  = zu[0]+zu[1]+zu[2]+zu[3]+zu[4];
    mu = wredsum(s) * inv320;
    vs = 0.f;
#pragma unroll
    for (int i = 0; i < 5; ++i) { float d = zu[i]-mu; vs += d*d; }
    inv = rsqrtf(wredsum(vs)*inv320 + 1e-5f);
    float u[5];
#pragma unroll
    for (int i = 0; i < 5; ++i) {
        const int j = lane + i*64;
        u[i] = sigmoidf_((zu[i]-mu)*inv * lng[(l2*3+1)*H_ + j] + lnb[(l2*3+1)*H_ + j]);
    }
    float z2[5];
#pragma unroll
    for (int i = 0; i < 5; ++i) z2[i] = zn[i] + r[i]*hn[i];
    s  = z2[0]+z2[1]+z2[2]+z2[3]+z2[4];
    mu = wredsum(s) * inv320;
    vs = 0.f;
#pragma unroll
    for (int i = 0; i < 5; ++i) { float d = z2[i]-mu; vs += d*d; }
    inv = rsqrtf(wredsum(vs)*inv320 + 1e-5f);
#pragma unroll
    for (int i = 0; i < 5; ++i) {
        const int j = lane + i*64;
        float nv = tanhf((z2[i]-mu)*inv * lng[(l2*3+2)*H_ + j] + lnb[(l2*3+2)*H_ + j]);
        float hp;
        if constexpr (REGH) hp = hreg[i];
        else                hp = state[(size_t)l2*BH_ + (size_t)b2*H_ + j];
        float hv = (1.0f - u[i])*nv + u[i]*hp;
        if constexpr (REGH) hreg[i] = hv;
        else                state[(size_t)l2*BH_ + (size_t)b2*H_ + j] = hv;
        frow[j] = (_Float16)hv;                       // plain write-through store
        if (l2 == 2)    out[((size_t)b2*T_ + t2)*H_ + j] = hv;
        if (t2 == T_-1) out[(size_t)BTH_ + ((size_t)l2*B_ + b2)*H_ + j] = hv;
    }
}

// ---- init: zero barrier area, copy h0 into fp32 state (fallback) + f16 ----
__global__ void k_init(const float* __restrict__ h0, float* __restrict__ ws) {
    float*     state = ws + OFF_STATE;
    _Float16*  stf   = (_Float16*)(ws + OFF_STF);
    unsigned*  bar   = (unsigned*)(ws + OFF_BAR);
    int gt = blockIdx.x*blockDim.x + threadIdx.x;
    for (int i = gt; i < BAR_WORDS; i += gridDim.x*blockDim.x) bar[i] = 0u;
    for (int i = gt; i < L_*BH_; i += gridDim.x*blockDim.x) {
        float v = h0[i];
        state[i] = v;
        stf[i]   = (_Float16)v;
    }
}

// ======================= cooperative persistent kernel =======================
__launch_bounds__(NTHR, 2)
__global__ void gru_coop_kernel(const float* __restrict__ x,
                                const float* __restrict__ h0,
                                const float* __restrict__ rmean,
                                const float* __restrict__ rvar,
                                const float* __restrict__ wih0,
                                const float* __restrict__ wihr,
                                const float* __restrict__ whh,
                                const float* __restrict__ bih,
                                const float* __restrict__ bhh,
                                const float* __restrict__ lng,
                                const float* __restrict__ lnb,
                                float* __restrict__ out,
                                float* __restrict__ ws)
{
    cg::grid_group grid = cg::this_grid();

    float*     zbuf  = ws + OFF_Z;
    float*     hnbuf = ws + OFF_HN;
    _Float16*  stf   = (_Float16*)(ws + OFF_STF);
    unsigned*  bar   = (unsigned*)(ws + OFF_BAR);
    unsigned*  det   = bar;                      // [NBLK]

    const int tid = threadIdx.x;
    const int bid = blockIdx.x;

    __shared__ _Float16 w_lds[CPB_][WSTR];       // 62208 B (scratch overlay first)
    __shared__ float    nrm_lds[2][KIP0];        //  1792 B
    __shared__ int      sh_g, sh_idx, sh_fast;

    // ---- publish measured XCD, grid-sync, self-organize groups ----
    unsigned myxcd;
    asm volatile("s_getreg_b32 %0, hwreg(HW_REG_XCC_ID)" : "=s"(myxcd));
    if (tid == 0) astore(&det[bid], (myxcd & 7u) + 1u);
    grid.sync();

    unsigned* det_l = (unsigned*)w_lds;          // scratch overlay (before weights)
    for (int i = tid; i < NBLK; i += NTHR) det_l[i] = det[i];
    __syncthreads();
    if (tid == 0) {
        int myx = (int)(det_l[bid] - 1u) & 7;
        int cnt[8] = {0,0,0,0,0,0,0,0};
        int rank = 0;
        for (int i = 0; i < NBLK; ++i) {
            int xx = (int)(det_l[i] - 1u) & 7;
            if (xx == myx && i < bid) ++rank;
            ++cnt[xx];
        }
        int p = 0, chunk_of[8];
        for (int xx = 0; xx < 8; ++xx) chunk_of[xx] = (cnt[xx] >= SPG_) ? p++ : -1;
        if (cnt[myx] >= SPG_ && rank < SPG_) {
            sh_g = chunk_of[myx]; sh_idx = rank; sh_fast = 1;
        } else {
            int ord = 0; int c2[8] = {0,0,0,0,0,0,0,0};
            for (int i = 0; i < bid; ++i) {
                int xx = (int)(det_l[i] - 1u) & 7;
                bool pu = (cnt[xx] >= SPG_) && (c2[xx] < SPG_);
                ++c2[xx];
                if (!pu) ++ord;
            }
            sh_g = p + ord / SPG_; sh_idx = ord % SPG_; sh_fast = 0;
        }
    }
    __syncthreads();
    const int  g    = sh_g;
    const int  idx  = sh_idx;
    const bool fast = (sh_fast != 0);
    const int  l    = idx / NCG_;
    const int  cgp  = idx - l*NCG_;
    const int  colbase = cgp * CPB_;
    unsigned*  greg = bar + 512 + g*GRP_STR;

    load_weights(l, colbase, tid, wih0, wihr, whh, rmean, rvar, w_lds, nrm_lds);

    const int wid  = tid >> 6;
    const int lane = tid & 63;
    const int wv   = idx*4 + wid;

    // hidden state for this wave's phase-2 task lives in registers
    float hreg[5] = {0.f, 0.f, 0.f, 0.f, 0.f};
    if (wv < L_*RPG_) {
        const int l2 = wv >> 5, row = wv & 31, b2 = g*RPG_ + row;
#pragma unroll
        for (int i = 0; i < 5; ++i)
            hreg[i] = h0[(size_t)l2*BH_ + (size_t)b2*H_ + lane + i*64];
    }

    for (int tau = 0; tau < T_ + L_ - 1; ++tau) {
        const int t = tau - l;
        if (t >= 0 && t < T_)
            phase1_dispatch(g, l, t, colbase, tid, x, stf, bih, bhh,
                            zbuf, hnbuf, w_lds, nrm_lds);
        group_barrier(greg, idx, tid, (unsigned)(2*tau + 1), fast);
        phase2_work<true>(g, tau, wv, lane, lng, lnb, nullptr, hreg,
                          stf, zbuf, hnbuf, out);
        group_barrier(greg, idx, tid, (unsigned)(2*tau + 2), fast);
    }
}

// ======================= non-cooperative fallback path =======================
__launch_bounds__(NTHR)
__global__ void k_p1(const float* __restrict__ x,
                     const float* __restrict__ rmean, const float* __restrict__ rvar,
                     const float* __restrict__ wih0,  const float* __restrict__ wihr,
                     const float* __restrict__ whh,   const float* __restrict__ bih,
                     const float* __restrict__ bhh,   float* __restrict__ ws, int tau)
{
    const int tid = threadIdx.x;
    const int bid = blockIdx.x;
    const int g   = bid & (GR_ - 1);
    const int idx = bid >> 3;
    const int l   = idx / NCG_;
    const int cgp = idx - l*NCG_;
    const int colbase = cgp * CPB_;
    const int t = tau - l;
    if (t < 0 || t >= T_) return;

    float*    zbuf  = ws + OFF_Z;
    float*    hnbuf = ws + OFF_HN;
    _Float16* stf   = (_Float16*)(ws + OFF_STF);

    __shared__ _Float16 w_lds[CPB_][WSTR];
    __shared__ float    nrm_lds[2][KIP0];
    load_weights(l, colbase, tid, wih0, wihr, whh, rmean, rvar, w_lds, nrm_lds);
    phase1_dispatch(g, l, t, colbase, tid, x, stf, bih, bhh, zbuf, hnbuf, w_lds, nrm_lds);
}

__launch_bounds__(NTHR)
__global__ void k_p2(const float* __restrict__ lng, const float* __restrict__ lnb,
                     float* __restrict__ ws, float* __restrict__ out, int tau)
{
    float*    state = ws + OFF_STATE;
    float*    zbuf  = ws + OFF_Z;
    float*    hnbuf = ws + OFF_HN;
    _Float16* stf   = (_Float16*)(ws + OFF_STF);
    const int bid = blockIdx.x;
    const int g   = bid & (GR_ - 1);
    const int idx = bid >> 3;
    phase2_work<false>(g, tau, idx*4 + (threadIdx.x >> 6), threadIdx.x & 63,
                       lng, lnb, state, nullptr, stf, zbuf, hnbuf, out);
}

extern "C" void kernel_launch(void* const* d_in, const int* in_sizes, int n_in,
                              void* d_out, int out_size, void* d_ws, size_t ws_size,
                              hipStream_t stream) {
    (void)in_sizes; (void)n_in; (void)out_size; (void)ws_size;
    const float* x     = (const float*)d_in[0];
    const float* h0    = (const float*)d_in[1];
    const float* rmean = (const float*)d_in[2];
    const float* rvar  = (const float*)d_in[3];
    const float* wih0  = (const float*)d_in[4];
    const float* wihr  = (const float*)d_in[5];
    const float* whh   = (const float*)d_in[6];
    const float* bih   = (const float*)d_in[7];
    const float* bhh   = (const float*)d_in[8];
    const float* lng   = (const float*)d_in[9];
    const float* lnb   = (const float*)d_in[10];
    float* out = (float*)d_out;
    float* ws  = (float*)d_ws;

    k_init<<<dim3(240), dim3(NTHR), 0, stream>>>(h0, ws);

    int ncu = 0, nb = 0;
    hipDeviceGetAttribute(&ncu, hipDeviceAttributeMultiprocessorCount, 0);
    hipError_t qerr = hipOccupancyMaxActiveBlocksPerMultiprocessor(
        &nb, (const void*)gru_coop_kernel, NTHR, 0);
    const bool coop_ok = (qerr == hipSuccess) && (nb > 0) &&
                         ((long long)nb * (long long)ncu >= NBLK);

    if (coop_ok) {
        void* args[13] = {
            (void*)&x, (void*)&h0, (void*)&rmean, (void*)&rvar,
            (void*)&wih0, (void*)&wihr, (void*)&whh,
            (void*)&bih, (void*)&bhh, (void*)&lng, (void*)&lnb,
            (void*)&out, (void*)&ws
        };
        hipLaunchCooperativeKernel((void*)gru_coop_kernel,
                                   dim3(NBLK), dim3(NTHR), args, 0, stream);
    } else {
        for (int tau = 0; tau < T_ + L_ - 1; ++tau) {
            k_p1<<<dim3(NBLK), dim3(NTHR), 0, stream>>>(
                x, rmean, rvar, wih0, wihr, whh, bih, bhh, ws, tau);
            k_p2<<<dim3(NBLK), dim3(NTHR), 0, stream>>>(lng, lnb, ws, out, tau);
        }
    }
}

// Round 8
// 22661.842 us; speedup vs baseline: 1.2380x; 1.0013x over previous
//
#include <hip/hip_runtime.h>
#include <hip/hip_fp16.h>
#include <hip/hip_cooperative_groups.h>

namespace cg = cooperative_groups;

#define B_   256
#define T_   512
#define D_   200
#define H_   320
#define L_   3
#define G3_  960
#define BH_  (B_*H_)
#define BTH_ (B_*T_*H_)

#define GR_   8              // groups (batch split); one per XCD when pure
#define RPG_  32             // rows (batch) per group
#define CPB_  48             // output cols per block
#define NCG_  20             // col-groups per layer (960/48)
#define SPG_  60             // working blocks per group (3 layers * 20)
#define NBLK_MAX 512         // fill ALL resident slots (2/CU x 256 CU)
#define NTHR  256
#define KIP0  224            // layer-0 input K padded to 32-multiple
#define WSTR  648            // LDS weight row stride in f16 elems

typedef _Float16 half8 __attribute__((ext_vector_type(8)));
typedef float    f32x4 __attribute__((ext_vector_type(4)));

// ---- ws layout (floats) ----
#define OFF_STATE 0
#define SZ_STATE  (L_*BH_)                 // fp32 hidden state (fallback path only)
#define OFF_Z     (OFF_STATE + SZ_STATE)
#define SZ_Z      (L_*B_*G3_)
#define OFF_HN    (OFF_Z + SZ_Z)
#define SZ_HN     (L_*B_*H_)
#define OFF_STF   (OFF_HN + SZ_HN)         // f16 hidden state copy
#define SZ_STF_F  ((L_*BH_)/2)
#define OFF_BAR   (OFF_STF + SZ_STF_F)
// barrier area (u32 words): det[512] @0, then 8 group regions
#define FLAG_STR  16
#define EPOCH_OFF (SPG_*FLAG_STR)          // 960
#define GRP_STR   1024
#define BAR_WORDS (512 + GR_*GRP_STR)      // 8704

__device__ __forceinline__ float sigmoidf_(float v) {
    return 1.0f / (1.0f + __expf(-v));
}

__device__ __forceinline__ float wredsum(float v) {
#pragma unroll
    for (int m = 32; m > 0; m >>= 1) v += __shfl_xor(v, m, 64);
    return v;
}

__device__ __forceinline__ half8 h8zero() {
    half8 a;
#pragma unroll
    for (int j = 0; j < 8; ++j) a[j] = (_Float16)0.f;
    return a;
}

__device__ __forceinline__ unsigned aload(const unsigned* p) {
    return __hip_atomic_load(p, __ATOMIC_RELAXED, __HIP_MEMORY_SCOPE_AGENT);
}
__device__ __forceinline__ unsigned armw(unsigned* p) {
    return __hip_atomic_fetch_add(p, 0u, __ATOMIC_RELAXED, __HIP_MEMORY_SCOPE_AGENT);
}
__device__ __forceinline__ void astore(unsigned* p, unsigned v) {
    __hip_atomic_store(p, v, __ATOMIC_RELAXED, __HIP_MEMORY_SCOPE_AGENT);
}

// ---------------- group barrier ----------------
// greg: flags at [idx*FLAG_STR], epoch at [EPOCH_OFF]. token strictly increasing.
// fast (all SPG_ blocks on ONE XCD): plain stores are already in the shared L2
// (write-through vL1 + vmcnt drain in __syncthreads). Arrival = relaxed agent
// atomic flag; leader wave scans flags in parallel; exit = vL1-only buffer_inv.
// safe (any placement): agent fences around the same protocol (r4-proven).
__device__ __forceinline__ void group_barrier(unsigned* greg, int idx, int tid,
                                              unsigned token, bool fast) {
    __syncthreads();
    if (!fast && tid == 0) __threadfence();            // release (wbl2)
    if (tid == 0) astore(&greg[idx*FLAG_STR], token);
    if (idx == 0) {
        if (tid < SPG_) {                              // wave-0 lanes poll in parallel
            unsigned* f = &greg[tid*FLAG_STR];
            int spin = 0;
            for (;;) {
                unsigned v = ((++spin & 63) == 0) ? armw(f) : aload(f);
                if ((int)(v - token) >= 0) break;
                __builtin_amdgcn_s_sleep(1);
            }
        }
        if (tid == 0) astore(&greg[EPOCH_OFF], token);
    } else if (tid == 0) {
        unsigned* e = &greg[EPOCH_OFF];
        int spin = 0;
        for (;;) {
            unsigned v = ((++spin & 63) == 0) ? armw(e) : aload(e);
            if ((int)(v - token) >= 0) break;
            __builtin_amdgcn_s_sleep(1);
        }
    }
    __syncthreads();
    if (fast) {
        asm volatile("buffer_inv" ::: "memory");       // vL1 only, every wave
    } else {
        if (tid == 0) __threadfence();                 // acquire (inv)
        __syncthreads();
    }
}

__device__ __forceinline__ void load_weights(int l, int colbase, int tid,
        const float* __restrict__ wih0, const float* __restrict__ wihr,
        const float* __restrict__ whh,  const float* __restrict__ rmean,
        const float* __restrict__ rvar,
        _Float16 (*w)[WSTR], float (*nrm)[KIP0])
{
    for (int e = tid; e < CPB_*WSTR; e += NTHR) ((_Float16*)w)[e] = (_Float16)0.f;
    if (l == 0) for (int e = tid; e < 2*KIP0; e += NTHR) ((float*)nrm)[e] = 0.f;
    __syncthreads();
    const int KI  = (l == 0) ? D_ : H_;
    const int KIP = (l == 0) ? KIP0 : H_;
    for (int e = tid; e < CPB_*KI; e += NTHR) {
        int c = e / KI, k = e - c*KI;
        float v = (l == 0) ? wih0[(size_t)(colbase + c)*D_ + k]
                           : wihr[((size_t)(l-1)*G3_ + colbase + c)*H_ + k];
        w[c][k] = (_Float16)v;
    }
    for (int e = tid; e < CPB_*H_; e += NTHR) {
        int c = e / H_, k = e - c*H_;
        w[c][KIP + k] = (_Float16)whh[((size_t)l*G3_ + colbase + c)*H_ + k];
    }
    if (l == 0) {
        for (int k = tid; k < D_; k += NTHR) {
            nrm[0][k] = rmean[k];
            nrm[1][k] = rsqrtf(rvar[k] + 1e-8f);
        }
    }
    __syncthreads();
}

template<int KTI, bool L0>
__device__ __forceinline__ void phase1_work(int g, int l, int t, int colbase, int tid,
        const float* __restrict__ x, const _Float16* __restrict__ stf,
        const float* __restrict__ bih, const float* __restrict__ bhh,
        float* __restrict__ zbuf, float* __restrict__ hnbuf,
        const _Float16 (*w)[WSTR], const float (*nrm)[KIP0])
{
    const int wid  = tid >> 6;       // 0 or 1 (callers gate wid<2)
    const int lane = tid & 63;
    const int nr   = lane & 15;
    const int grp  = lane >> 4;
    const int mb   = g*RPG_ + wid*16;
    constexpr int KIP = KTI * 32;

    f32x4 accI[3], accH[3];
#pragma unroll
    for (int nt = 0; nt < 3; ++nt) {
#pragma unroll
        for (int r = 0; r < 4; ++r) { accI[nt][r] = 0.f; accH[nt][r] = 0.f; }
    }

    // ---------- input-to-hidden ----------
#pragma unroll
    for (int kt = 0; kt < KTI; ++kt) {
        const int k0 = kt*32 + grp*8;
        half8 a;
        if (L0) {
            if (kt == KTI-1 && grp > 0) {
                a = h8zero();
            } else {
                const float* xr = &x[((size_t)(mb + nr)*T_ + t)*D_ + k0];
                float xv[8];
                *(float4*)&xv[0] = *(const float4*)xr;
                *(float4*)&xv[4] = *(const float4*)(xr + 4);
#pragma unroll
                for (int j = 0; j < 8; ++j) {
                    float nv = (xv[j] - nrm[0][k0+j]) * nrm[1][k0+j];
                    a[j] = (_Float16)fminf(fmaxf(nv, -10.f), 10.f);
                }
            }
        } else {
            a = *(const half8*)&stf[(size_t)(l-1)*BH_ + (size_t)(mb + nr)*H_ + k0];
        }
#pragma unroll
        for (int nt = 0; nt < 3; ++nt) {
            half8 bf = *(const half8*)&w[nt*16 + nr][k0];
            accI[nt] = __builtin_amdgcn_mfma_f32_16x16x32_f16(a, bf, accI[nt], 0, 0, 0);
        }
    }
    // ---------- hidden-to-hidden (K = 320) ----------
#pragma unroll
    for (int kt = 0; kt < 10; ++kt) {
        const int k0 = kt*32 + grp*8;
        half8 a = *(const half8*)&stf[(size_t)l*BH_ + (size_t)(mb + nr)*H_ + k0];
#pragma unroll
        for (int nt = 0; nt < 3; ++nt) {
            half8 bf = *(const half8*)&w[nt*16 + nr][KIP + k0];
            accH[nt] = __builtin_amdgcn_mfma_f32_16x16x32_f16(a, bf, accH[nt], 0, 0, 0);
        }
    }
    // ---------- store pre-activations (plain stores; write-through to L2) ----------
#pragma unroll
    for (int nt = 0; nt < 3; ++nt) {
        const int col = colbase + nt*16 + nr;
        const float bi = bih[l*G3_ + col];
        const float bh = bhh[l*G3_ + col];
        const bool ru = (colbase + nt*16) < 2*H_;
#pragma unroll
        for (int r = 0; r < 4; ++r) {
            const int m = mb + grp*4 + r;
            const size_t zi = ((size_t)l*B_ + m)*G3_ + col;
            if (ru) {
                zbuf[zi] = accI[nt][r] + accH[nt][r] + bi + bh;
            } else {
                zbuf[zi] = accI[nt][r] + bi;
                hnbuf[((size_t)l*B_ + m)*H_ + (col - 2*H_)] = accH[nt][r] + bh;
            }
        }
    }
}

__device__ __forceinline__ void phase1_dispatch(int g, int l, int t, int colbase, int tid,
        const float* x, const _Float16* stf, const float* bih, const float* bhh,
        float* zbuf, float* hnbuf, const _Float16 (*w)[WSTR], const float (*nrm)[KIP0])
{
    if ((tid >> 6) >= 2) return;   // 2 waves of 16 rows cover RPG_=32
    if (l == 0) phase1_work<7,  true >(g, l, t, colbase, tid, x, stf, bih, bhh, zbuf, hnbuf, w, nrm);
    else        phase1_work<10, false>(g, l, t, colbase, tid, x, stf, bih, bhh, zbuf, hnbuf, w, nrm);
}

// REGH=true: h in caller registers (coop kernel). false: fp32 state buffer (fallback).
template<bool REGH>
__device__ __forceinline__ void phase2_work(int g, int tau, int wv, int lane,
        const float* __restrict__ lng, const float* __restrict__ lnb,
        float* __restrict__ state, float* hreg,
        _Float16* __restrict__ stf,
        const float* __restrict__ zbuf, const float* __restrict__ hnbuf,
        float* __restrict__ out)
{
    if (wv >= L_*RPG_) return;            // 96 tasks per group
    const int l2  = wv >> 5;
    const int row = wv & 31;
    const int b2  = g*RPG_ + row;
    const int t2  = tau - l2;
    if (t2 < 0 || t2 >= T_) return;

    const float* zrow  = &zbuf[((size_t)l2*B_ + b2)*G3_];
    const float* hnrow = &hnbuf[((size_t)l2*B_ + b2)*H_];
    _Float16*    frow  = &stf[(size_t)l2*BH_ + (size_t)b2*H_];

    float zr[5], zu[5], zn[5], hn[5];
#pragma unroll
    for (int i = 0; i < 5; ++i) {
        const int j = lane + i*64;
        zr[i] = zrow[j];
        zu[i] = zrow[320 + j];
        zn[i] = zrow[640 + j];
        hn[i] = hnrow[j];
    }
    const float inv320 = 1.0f/320.0f;
    float s  = zr[0]+zr[1]+zr[2]+zr[3]+zr[4];
    float mu = wredsum(s) * inv320;
    float vs = 0.f;
#pragma unroll
    for (int i = 0; i < 5; ++i) { float d = zr[i]-mu; vs += d*d; }
    float inv = rsqrtf(wredsum(vs)*inv320 + 1e-5f);
    float r[5];
#pragma unroll
    for (int i = 0; i < 5; ++i) {
        const int j = lane + i*64;
        r[i] = sigmoidf_((zr[i]-mu)*inv * lng[(l2*3+0)*H_ + j] + lnb[(l2*3+0)*H_ + j]);
    }
    s  = zu[0]+zu[1]+zu[2]+zu[3]+zu[4];
    mu = wredsum(s) * inv320;
    vs = 0.f;
#pragma unroll
    for (int i = 0; i < 5; ++i) { float d = zu[i]-mu; vs += d*d; }
    inv = rsqrtf(wredsum(vs)*inv320 + 1e-5f);
    float u[5];
#pragma unroll
    for (int i = 0; i < 5; ++i) {
        const int j = lane + i*64;
        u[i] = sigmoidf_((zu[i]-mu)*inv * lng[(l2*3+1)*H_ + j] + lnb[(l2*3+1)*H_ + j]);
    }
    float z2[5];
#pragma unroll
    for (int i = 0; i < 5; ++i) z2[i] = zn[i] + r[i]*hn[i];
    s  = z2[0]+z2[1]+z2[2]+z2[3]+z2[4];
    mu = wredsum(s) * inv320;
    vs = 0.f;
#pragma unroll
    for (int i = 0; i < 5; ++i) { float d = z2[i]-mu; vs += d*d; }
    inv = rsqrtf(wredsum(vs)*inv320 + 1e-5f);
#pragma unroll
    for (int i = 0; i < 5; ++i) {
        const int j = lane + i*64;
        float nv = tanhf((z2[i]-mu)*inv * lng[(l2*3+2)*H_ + j] + lnb[(l2*3+2)*H_ + j]);
        float hp;
        if constexpr (REGH) hp = hreg[i];
        else                hp = state[(size_t)l2*BH_ + (size_t)b2*H_ + j];
        float hv = (1.0f - u[i])*nv + u[i]*hp;
        if constexpr (REGH) hreg[i] = hv;
        else                state[(size_t)l2*BH_ + (size_t)b2*H_ + j] = hv;
        frow[j] = (_Float16)hv;                       // plain write-through store
        if (l2 == 2)    out[((size_t)b2*T_ + t2)*H_ + j] = hv;
        if (t2 == T_-1) out[(size_t)BTH_ + ((size_t)l2*B_ + b2)*H_ + j] = hv;
    }
}

// ---- init: zero barrier area, copy h0 into fp32 state (fallback) + f16 ----
__global__ void k_init(const float* __restrict__ h0, float* __restrict__ ws) {
    float*     state = ws + OFF_STATE;
    _Float16*  stf   = (_Float16*)(ws + OFF_STF);
    unsigned*  bar   = (unsigned*)(ws + OFF_BAR);
    int gt = blockIdx.x*blockDim.x + threadIdx.x;
    for (int i = gt; i < BAR_WORDS; i += gridDim.x*blockDim.x) bar[i] = 0u;
    for (int i = gt; i < L_*BH_; i += gridDim.x*blockDim.x) {
        float v = h0[i];
        state[i] = v;
        stf[i]   = (_Float16)v;
    }
}

// ======================= cooperative persistent kernel =======================
__launch_bounds__(NTHR, 2)
__global__ void gru_coop_kernel(const float* __restrict__ x,
                                const float* __restrict__ h0,
                                const float* __restrict__ rmean,
                                const float* __restrict__ rvar,
                                const float* __restrict__ wih0,
                                const float* __restrict__ wihr,
                                const float* __restrict__ whh,
                                const float* __restrict__ bih,
                                const float* __restrict__ bhh,
                                const float* __restrict__ lng,
                                const float* __restrict__ lnb,
                                float* __restrict__ out,
                                float* __restrict__ ws,
                                int nblk)
{
    cg::grid_group grid = cg::this_grid();

    float*     zbuf  = ws + OFF_Z;
    float*     hnbuf = ws + OFF_HN;
    _Float16*  stf   = (_Float16*)(ws + OFF_STF);
    unsigned*  bar   = (unsigned*)(ws + OFF_BAR);
    unsigned*  det   = bar;                      // [nblk] <= 512

    const int tid = threadIdx.x;
    const int bid = blockIdx.x;

    __shared__ _Float16 w_lds[CPB_][WSTR];       // 62208 B (scratch overlay first)
    __shared__ float    nrm_lds[2][KIP0];        //  1792 B
    __shared__ int      sh_g, sh_idx, sh_fast;

    // ---- publish measured XCD, grid-sync, self-organize groups ----
    unsigned myxcd;
    asm volatile("s_getreg_b32 %0, hwreg(HW_REG_XCC_ID)" : "=s"(myxcd));
    if (tid == 0) astore(&det[bid], (myxcd & 7u) + 1u);
    grid.sync();

    unsigned* det_l = (unsigned*)w_lds;          // scratch overlay (before weights)
    for (int i = tid; i < nblk; i += NTHR) det_l[i] = det[i];
    __syncthreads();
    if (tid == 0) {
        int myx = (int)(det_l[bid] - 1u) & 7;
        int cnt[8] = {0,0,0,0,0,0,0,0};
        int rank = 0;
        for (int i = 0; i < nblk; ++i) {
            int xx = (int)(det_l[i] - 1u) & 7;
            if (xx == myx && i < bid) ++rank;
            ++cnt[xx];
        }
        int p = 0, chunk_of[8];
        for (int xx = 0; xx < 8; ++xx) chunk_of[xx] = (cnt[xx] >= SPG_) ? p++ : -1;
        int gg, ii, ff;
        if (cnt[myx] >= SPG_ && rank < SPG_) {
            gg = chunk_of[myx]; ii = rank; ff = 1;
        } else {
            int ord = 0; int c2[8] = {0,0,0,0,0,0,0,0};
            for (int i = 0; i < bid; ++i) {
                int xx = (int)(det_l[i] - 1u) & 7;
                bool pu = (cnt[xx] >= SPG_) && (c2[xx] < SPG_);
                ++c2[xx];
                if (!pu) ++ord;
            }
            gg = p + ord / SPG_; ii = ord % SPG_; ff = 0;
        }
        sh_g = (gg < GR_) ? gg : -1;             // surplus blocks -> idle
        sh_idx = ii; sh_fast = ff;
    }
    __syncthreads();
    if (sh_g < 0) return;                        // idle (after grid.sync; safe)
    const int  g    = sh_g;
    const int  idx  = sh_idx;
    const bool fast = (sh_fast != 0);
    const int  l    = idx / NCG_;
    const int  cgp  = idx - l*NCG_;
    const int  colbase = cgp * CPB_;
    unsigned*  greg = bar + 512 + g*GRP_STR;

    load_weights(l, colbase, tid, wih0, wihr, whh, rmean, rvar, w_lds, nrm_lds);

    const int wid  = tid >> 6;
    const int lane = tid & 63;
    const int wv   = idx*4 + wid;

    // hidden state for this wave's phase-2 task lives in registers
    float hreg[5] = {0.f, 0.f, 0.f, 0.f, 0.f};
    if (wv < L_*RPG_) {
        const int l2 = wv >> 5, row = wv & 31, b2 = g*RPG_ + row;
#pragma unroll
        for (int i = 0; i < 5; ++i)
            hreg[i] = h0[(size_t)l2*BH_ + (size_t)b2*H_ + lane + i*64];
    }

    for (int tau = 0; tau < T_ + L_ - 1; ++tau) {
        const int t = tau - l;
        if (t >= 0 && t < T_)
            phase1_dispatch(g, l, t, colbase, tid, x, stf, bih, bhh,
                            zbuf, hnbuf, w_lds, nrm_lds);
        group_barrier(greg, idx, tid, (unsigned)(2*tau + 1), fast);
        phase2_work<true>(g, tau, wv, lane, lng, lnb, nullptr, hreg,
                          stf, zbuf, hnbuf, out);
        group_barrier(greg, idx, tid, (unsigned)(2*tau + 2), fast);
    }
}

// ======================= non-cooperative fallback path =======================
__launch_bounds__(NTHR)
__global__ void k_p1(const float* __restrict__ x,
                     const float* __restrict__ rmean, const float* __restrict__ rvar,
                     const float* __restrict__ wih0,  const float* __restrict__ wihr,
                     const float* __restrict__ whh,   const float* __restrict__ bih,
                     const float* __restrict__ bhh,   float* __restrict__ ws, int tau)
{
    const int tid = threadIdx.x;
    const int bid = blockIdx.x;
    const int g   = bid & (GR_ - 1);
    const int idx = bid >> 3;
    const int l   = idx / NCG_;
    const int cgp = idx - l*NCG_;
    const int colbase = cgp * CPB_;
    const int t = tau - l;
    if (t < 0 || t >= T_) return;

    float*    zbuf  = ws + OFF_Z;
    float*    hnbuf = ws + OFF_HN;
    _Float16* stf   = (_Float16*)(ws + OFF_STF);

    __shared__ _Float16 w_lds[CPB_][WSTR];
    __shared__ float    nrm_lds[2][KIP0];
    load_weights(l, colbase, tid, wih0, wihr, whh, rmean, rvar, w_lds, nrm_lds);
    phase1_dispatch(g, l, t, colbase, tid, x, stf, bih, bhh, zbuf, hnbuf, w_lds, nrm_lds);
}

__launch_bounds__(NTHR)
__global__ void k_p2(const float* __restrict__ lng, const float* __restrict__ lnb,
                     float* __restrict__ ws, float* __restrict__ out, int tau)
{
    float*    state = ws + OFF_STATE;
    float*    zbuf  = ws + OFF_Z;
    float*    hnbuf = ws + OFF_HN;
    _Float16* stf   = (_Float16*)(ws + OFF_STF);
    const int bid = blockIdx.x;
    const int g   = bid & (GR_ - 1);
    const int idx = bid >> 3;
    phase2_work<false>(g, tau, idx*4 + (threadIdx.x >> 6), threadIdx.x & 63,
                       lng, lnb, state, nullptr, stf, zbuf, hnbuf, out);
}

extern "C" void kernel_launch(void* const* d_in, const int* in_sizes, int n_in,
                              void* d_out, int out_size, void* d_ws, size_t ws_size,
                              hipStream_t stream) {
    (void)in_sizes; (void)n_in; (void)out_size; (void)ws_size;
    const float* x     = (const float*)d_in[0];
    const float* h0    = (const float*)d_in[1];
    const float* rmean = (const float*)d_in[2];
    const float* rvar  = (const float*)d_in[3];
    const float* wih0  = (const float*)d_in[4];
    const float* wihr  = (const float*)d_in[5];
    const float* whh   = (const float*)d_in[6];
    const float* bih   = (const float*)d_in[7];
    const float* bhh   = (const float*)d_in[8];
    const float* lng   = (const float*)d_in[9];
    const float* lnb   = (const float*)d_in[10];
    float* out = (float*)d_out;
    float* ws  = (float*)d_ws;

    k_init<<<dim3(240), dim3(NTHR), 0, stream>>>(h0, ws);

    int ncu = 0, nb = 0;
    hipDeviceGetAttribute(&ncu, hipDeviceAttributeMultiprocessorCount, 0);
    hipError_t qerr = hipOccupancyMaxActiveBlocksPerMultiprocessor(
        &nb, (const void*)gru_coop_kernel, NTHR, 0);
    long long cap = (long long)nb * (long long)ncu;
    int nblk = (cap >= NBLK_MAX) ? NBLK_MAX : (GR_*SPG_);   // 512, else 480
    const bool coop_ok = (qerr == hipSuccess) && (cap >= (long long)(GR_*SPG_));

    if (coop_ok) {
        void* args[14] = {
            (void*)&x, (void*)&h0, (void*)&rmean, (void*)&rvar,
            (void*)&wih0, (void*)&wihr, (void*)&whh,
            (void*)&bih, (void*)&bhh, (void*)&lng, (void*)&lnb,
            (void*)&out, (void*)&ws, (void*)&nblk
        };
        hipLaunchCooperativeKernel((void*)gru_coop_kernel,
                                   dim3(nblk), dim3(NTHR), args, 0, stream);
    } else {
        for (int tau = 0; tau < T_ + L_ - 1; ++tau) {
            k_p1<<<dim3(GR_*SPG_), dim3(NTHR), 0, stream>>>(
                x, rmean, rvar, wih0, wihr, whh, bih, bhh, ws, tau);
            k_p2<<<dim3(GR_*SPG_), dim3(NTHR), 0, stream>>>(lng, lnb, ws, out, tau);
        }
    }
}

// Round 11
// 10766.149 us; speedup vs baseline: 2.6058x; 2.1049x over previous
//
#include <hip/hip_runtime.h>
#include <hip/hip_fp16.h>

#define B_   256
#define T_   512
#define D_   200
#define H_   320
#define L_   3
#define G3_  960
#define BH_  (B_*H_)
#define BTH_ (B_*T_*H_)

#define GR_   8              // groups (batch split)
#define RPG_  32             // rows (batch) per group
#define CPB_  48             // output cols per block
#define NCG_  20             // col-groups per layer (960/48)
#define SPG_  60             // blocks per group (3 layers * 20)
#define NBLK  480            // 2/CU co-residency proven on HW (r7/r8 rocprof)
#define NTHR  256
#define KIP0  224            // layer-0 input K padded to 32-multiple
#define WSTR  648            // LDS weight row stride in f16 elems

typedef _Float16 half8 __attribute__((ext_vector_type(8)));
typedef float    f32x4 __attribute__((ext_vector_type(4)));

// ---- ws layout (floats) ----
#define OFF_Z     0
#define SZ_Z      (L_*B_*G3_)
#define OFF_HN    (OFF_Z + SZ_Z)
#define SZ_HN     (L_*B_*H_)
#define OFF_STF   (OFF_HN + SZ_HN)         // f16 hidden state (cross-block, coherent)
#define SZ_STF_F  ((L_*BH_)/2)
#define OFF_BAR   (OFF_STF + SZ_STF_F)
#define GRP_STR   256                      // u32 words per group's barrier line
#define BAR_WORDS (GR_*GRP_STR)

__device__ __forceinline__ float sigmoidf_(float v) {
    return 1.0f / (1.0f + __expf(-v));
}

__device__ __forceinline__ float wredsum(float v) {
#pragma unroll
    for (int m = 32; m > 0; m >>= 1) v += __shfl_xor(v, m, 64);
    return v;
}

__device__ __forceinline__ half8 h8zero() {
    half8 a;
#pragma unroll
    for (int j = 0; j < 8; ++j) a[j] = (_Float16)0.f;
    return a;
}

// relaxed agent-scope (device-coherent, MALL-served) atomic helpers
__device__ __forceinline__ void stc(unsigned* p, unsigned v) {
    __hip_atomic_store(p, v, __ATOMIC_RELAXED, __HIP_MEMORY_SCOPE_AGENT);
}
__device__ __forceinline__ void stcf(float* p, float v) {
    stc((unsigned*)p, __builtin_bit_cast(unsigned, v));
}

// ---------------- fence-free group barrier (placement-independent) ----------
// Monotonic counter per group: after barrier #k completes, *cnt == k*SPG_.
// __syncthreads drains vmcnt (all coherent stores MALL-visible), then one
// relaxed agent fetch_add + relaxed poll. No wbl2, no inv, no buffer_inv:
// ALL cross-block data is accessed with sc0/sc1 ops that bypass local caches.
__device__ __forceinline__ void group_barrier(unsigned* cnt, int tid, unsigned token) {
    __syncthreads();
    if (tid == 0) {
        __hip_atomic_fetch_add(cnt, 1u, __ATOMIC_RELAXED, __HIP_MEMORY_SCOPE_AGENT);
        while ((int)(__hip_atomic_load(cnt, __ATOMIC_RELAXED, __HIP_MEMORY_SCOPE_AGENT)
                     - token*(unsigned)SPG_) < 0)
            __builtin_amdgcn_s_sleep(2);
    }
    __syncthreads();
}

__device__ __forceinline__ void load_weights(int l, int colbase, int tid,
        const float* __restrict__ wih0, const float* __restrict__ wihr,
        const float* __restrict__ whh,  const float* __restrict__ rmean,
        const float* __restrict__ rvar,
        _Float16 (*w)[WSTR], float (*nrm)[KIP0])
{
    for (int e = tid; e < CPB_*WSTR; e += NTHR) ((_Float16*)w)[e] = (_Float16)0.f;
    if (l == 0) for (int e = tid; e < 2*KIP0; e += NTHR) ((float*)nrm)[e] = 0.f;
    __syncthreads();
    const int KI  = (l == 0) ? D_ : H_;
    const int KIP = (l == 0) ? KIP0 : H_;
    for (int e = tid; e < CPB_*KI; e += NTHR) {
        int c = e / KI, k = e - c*KI;
        float v = (l == 0) ? wih0[(size_t)(colbase + c)*D_ + k]
                           : wihr[((size_t)(l-1)*G3_ + colbase + c)*H_ + k];
        w[c][k] = (_Float16)v;
    }
    for (int e = tid; e < CPB_*H_; e += NTHR) {
        int c = e / H_, k = e - c*H_;
        w[c][KIP + k] = (_Float16)whh[((size_t)l*G3_ + colbase + c)*H_ + k];
    }
    if (l == 0) {
        for (int k = tid; k < D_; k += NTHR) {
            nrm[0][k] = rmean[k];
            nrm[1][k] = rsqrtf(rvar[k] + 1e-8f);
        }
    }
    __syncthreads();
}

template<int KTI, bool L0>
__device__ __forceinline__ void phase1_work(int g, int l, int t, int colbase, int tid,
        const float* __restrict__ x, const _Float16* __restrict__ stf,
        const float* __restrict__ bih, const float* __restrict__ bhh,
        float* __restrict__ zbuf, float* __restrict__ hnbuf,
        const _Float16 (*w)[WSTR], const float (*nrm)[KIP0])
{
    const int wid  = tid >> 6;       // 0 or 1 (caller gates wid<2)
    const int lane = tid & 63;
    const int nr   = lane & 15;
    const int grp  = lane >> 4;
    const int mb   = g*RPG_ + wid*16;
    constexpr int KIP = KTI * 32;

    half8 aI[KTI];
    f32x4 rI[KTI];
    f32x4 rH[10];

    if (L0) {
        // x is a kernel input (read-only): plain cached loads + normalize+clamp
#pragma unroll
        for (int kt = 0; kt < KTI; ++kt) {
            if (kt == KTI-1 && grp > 0) { aI[kt] = h8zero(); continue; }
            const int k0 = kt*32 + grp*8;
            const float* xr = &x[((size_t)(mb + nr)*T_ + t)*D_ + k0];
            float xv[8];
            *(float4*)&xv[0] = *(const float4*)xr;
            *(float4*)&xv[4] = *(const float4*)(xr + 4);
#pragma unroll
            for (int j = 0; j < 8; ++j) {
                float nv = (xv[j] - nrm[0][k0+j]) * nrm[1][k0+j];
                aI[kt][j] = (_Float16)fminf(fmaxf(nv, -10.f), 10.f);
            }
        }
    } else {
        // cross-block hidden state: batch-issue MALL-coherent 16B loads
        const _Float16* srcI = &stf[(size_t)(l-1)*BH_ + (size_t)(mb + nr)*H_ + grp*8];
#pragma unroll
        for (int kt = 0; kt < KTI; ++kt)
            asm volatile("global_load_dwordx4 %0, %1, off offset:%2 sc0 sc1"
                         : "=&v"(rI[kt]) : "v"(srcI), "i"(kt*64));
    }
    {
        const _Float16* srcH = &stf[(size_t)l*BH_ + (size_t)(mb + nr)*H_ + grp*8];
#pragma unroll
        for (int kt = 0; kt < 10; ++kt)
            asm volatile("global_load_dwordx4 %0, %1, off offset:%2 sc0 sc1"
                         : "=&v"(rH[kt]) : "v"(srcH), "i"(kt*64));
    }
    asm volatile("s_waitcnt vmcnt(0)" ::: "memory");
    __builtin_amdgcn_sched_barrier(0);
    if (!L0) {
#pragma unroll
        for (int kt = 0; kt < KTI; ++kt) aI[kt] = __builtin_bit_cast(half8, rI[kt]);
    }

    f32x4 accI[3], accH[3];
#pragma unroll
    for (int nt = 0; nt < 3; ++nt) {
#pragma unroll
        for (int r = 0; r < 4; ++r) { accI[nt][r] = 0.f; accH[nt][r] = 0.f; }
    }

#pragma unroll
    for (int kt = 0; kt < KTI; ++kt) {
        const int k0 = kt*32 + grp*8;
#pragma unroll
        for (int nt = 0; nt < 3; ++nt) {
            half8 bf = *(const half8*)&w[nt*16 + nr][k0];
            accI[nt] = __builtin_amdgcn_mfma_f32_16x16x32_f16(aI[kt], bf, accI[nt], 0, 0, 0);
        }
    }
#pragma unroll
    for (int kt = 0; kt < 10; ++kt) {
        const int k0 = kt*32 + grp*8;
        half8 ah = __builtin_bit_cast(half8, rH[kt]);
#pragma unroll
        for (int nt = 0; nt < 3; ++nt) {
            half8 bf = *(const half8*)&w[nt*16 + nr][KIP + k0];
            accH[nt] = __builtin_amdgcn_mfma_f32_16x16x32_f16(ah, bf, accH[nt], 0, 0, 0);
        }
    }

    // ---- store pre-activations: coherent (MALL write-through) stores ----
#pragma unroll
    for (int nt = 0; nt < 3; ++nt) {
        const int col = colbase + nt*16 + nr;
        const float bi = bih[l*G3_ + col];
        const float bh = bhh[l*G3_ + col];
        const bool ru = (colbase + nt*16) < 2*H_;
#pragma unroll
        for (int r = 0; r < 4; ++r) {
            const int m = mb + grp*4 + r;
            const size_t zi = ((size_t)l*B_ + m)*G3_ + col;
            if (ru) {
                stcf(&zbuf[zi], accI[nt][r] + accH[nt][r] + bi + bh);
            } else {
                stcf(&zbuf[zi], accI[nt][r] + bi);
                stcf(&hnbuf[((size_t)l*B_ + m)*H_ + (col - 2*H_)], accH[nt][r] + bh);
            }
        }
    }
}

__device__ __forceinline__ void phase1_dispatch(int g, int l, int t, int colbase, int tid,
        const float* x, const _Float16* stf, const float* bih, const float* bhh,
        float* zbuf, float* hnbuf, const _Float16 (*w)[WSTR], const float (*nrm)[KIP0])
{
    if ((tid >> 6) >= 2) return;   // 2 waves of 16 rows cover RPG_=32
    if (l == 0) phase1_work<7,  true >(g, l, t, colbase, tid, x, stf, bih, bhh, zbuf, hnbuf, w, nrm);
    else        phase1_work<10, false>(g, l, t, colbase, tid, x, stf, bih, bhh, zbuf, hnbuf, w, nrm);
}

__device__ __forceinline__ void phase2_work(int g, int tau, int wv, int lane,
        const float* __restrict__ lng, const float* __restrict__ lnb,
        float* hreg, _Float16* __restrict__ stf,
        const float* __restrict__ zbuf, const float* __restrict__ hnbuf,
        float* __restrict__ out)
{
    if (wv >= L_*RPG_) return;            // 96 tasks per group
    const int l2  = wv >> 5;
    const int row = wv & 31;
    const int b2  = g*RPG_ + row;
    const int t2  = tau - l2;
    if (t2 < 0 || t2 >= T_) return;

    const float* zp   = &zbuf[((size_t)l2*B_ + b2)*G3_ + lane];
    const float* hp   = &hnbuf[((size_t)l2*B_ + b2)*H_ + lane];
    _Float16*    frow = &stf[(size_t)l2*BH_ + (size_t)b2*H_];

    // batch-issue all 20 coherent loads (coalesced 256B/instr), one waitcnt
    float zr[5], zu[5], zn[5], hn[5];
#pragma unroll
    for (int i = 0; i < 5; ++i) {
        asm volatile("global_load_dword %0, %1, off offset:%2 sc0 sc1"
                     : "=&v"(zr[i]) : "v"(zp), "i"(i*256));
        asm volatile("global_load_dword %0, %1, off offset:%2 sc0 sc1"
                     : "=&v"(zu[i]) : "v"(zp), "i"(1280 + i*256));
        asm volatile("global_load_dword %0, %1, off offset:%2 sc0 sc1"
                     : "=&v"(zn[i]) : "v"(zp), "i"(2560 + i*256));
        asm volatile("global_load_dword %0, %1, off offset:%2 sc0 sc1"
                     : "=&v"(hn[i]) : "v"(hp), "i"(i*256));
    }
    asm volatile("s_waitcnt vmcnt(0)" ::: "memory");
    __builtin_amdgcn_sched_barrier(0);

    const float inv320 = 1.0f/320.0f;
    float s  = zr[0]+zr[1]+zr[2]+zr[3]+zr[4];
    float mu = wredsum(s) * inv320;
    float vs = 0.f;
#pragma unroll
    for (int i = 0; i < 5; ++i) { float d = zr[i]-mu; vs += d*d; }
    float inv = rsqrtf(wredsum(vs)*inv320 + 1e-5f);
    float r[5];
#pragma unroll
    for (int i = 0; i < 5; ++i) {
        const int j = lane + i*64;
        r[i] = sigmoidf_((zr[i]-mu)*inv * lng[(l2*3+0)*H_ + j] + lnb[(l2*3+0)*H_ + j]);
    }
    s  = zu[0]+zu[1]+zu[2]+zu[3]+zu[4];
    mu = wredsum(s) * inv320;
    vs = 0.f;
#pragma unroll
    for (int i = 0; i < 5; ++i) { float d = zu[i]-mu; vs += d*d; }
    inv = rsqrtf(wredsum(vs)*inv320 + 1e-5f);
    float u[5];
#pragma unroll
    for (int i = 0; i < 5; ++i) {
        const int j = lane + i*64;
        u[i] = sigmoidf_((zu[i]-mu)*inv * lng[(l2*3+1)*H_ + j] + lnb[(l2*3+1)*H_ + j]);
    }
    float z2[5];
#pragma unroll
    for (int i = 0; i < 5; ++i) z2[i] = zn[i] + r[i]*hn[i];
    s  = z2[0]+z2[1]+z2[2]+z2[3]+z2[4];
    mu = wredsum(s) * inv320;
    vs = 0.f;
#pragma unroll
    for (int i = 0; i < 5; ++i) { float d = z2[i]-mu; vs += d*d; }
    inv = rsqrtf(wredsum(vs)*inv320 + 1e-5f);
#pragma unroll
    for (int i = 0; i < 5; ++i) {
        const int j = lane + i*64;
        float nv = tanhf((z2[i]-mu)*inv * lng[(l2*3+2)*H_ + j] + lnb[(l2*3+2)*H_ + j]);
        float hv = (1.0f - u[i])*nv + u[i]*hreg[i];
        hreg[i] = hv;
        // f16 state: pair adjacent lanes -> one coherent 4B store per even lane
        unsigned hb = (unsigned)__builtin_bit_cast(unsigned short, (_Float16)hv);
        unsigned ob = (unsigned)__shfl_xor((int)hb, 1, 64);
        if ((lane & 1) == 0)
            stc(&((unsigned*)frow)[j >> 1], (hb & 0xffffu) | (ob << 16));
        if (l2 == 2)    out[((size_t)b2*T_ + t2)*H_ + j] = hv;   // plain (host-read)
        if (t2 == T_-1) out[(size_t)BTH_ + ((size_t)l2*B_ + b2)*H_ + j] = hv;
    }
}

// ---- init: zero barrier counters, init f16 state from h0 ----
__global__ void k_init(const float* __restrict__ h0, float* __restrict__ ws) {
    _Float16*  stf = (_Float16*)(ws + OFF_STF);
    unsigned*  bar = (unsigned*)(ws + OFF_BAR);
    int gt = blockIdx.x*blockDim.x + threadIdx.x;
    for (int i = gt; i < BAR_WORDS; i += gridDim.x*blockDim.x) bar[i] = 0u;
    for (int i = gt; i < L_*BH_; i += gridDim.x*blockDim.x)
        stf[i] = (_Float16)h0[i];
}

// ================= persistent kernel (PLAIN launch, no grid.sync) ===========
// Co-residency of all 480 blocks (2/CU) is a measured hardware fact on this
// chip (r7/r8 rocprof: the 480-block dispatch ran at ~22% occupancy). The
// kernel contains NO grid-wide sync; only intra-group MALL-atomic barriers.
__launch_bounds__(NTHR, 2)
__global__ void gru_pers_kernel(const float* __restrict__ x,
                                const float* __restrict__ h0,
                                const float* __restrict__ rmean,
                                const float* __restrict__ rvar,
                                const float* __restrict__ wih0,
                                const float* __restrict__ wihr,
                                const float* __restrict__ whh,
                                const float* __restrict__ bih,
                                const float* __restrict__ bhh,
                                const float* __restrict__ lng,
                                const float* __restrict__ lnb,
                                float* __restrict__ out,
                                float* __restrict__ ws)
{
    float*     zbuf  = ws + OFF_Z;
    float*     hnbuf = ws + OFF_HN;
    _Float16*  stf   = (_Float16*)(ws + OFF_STF);
    unsigned*  bar   = (unsigned*)(ws + OFF_BAR);

    const int tid = threadIdx.x;
    const int bid = blockIdx.x;
    const int g   = bid & (GR_ - 1);     // any fixed mapping works (MALL-based sync)
    const int idx = bid >> 3;            // 0..59 within group
    const int l   = idx / NCG_;
    const int cgp = idx - l*NCG_;
    const int colbase = cgp * CPB_;

    unsigned* cnt = bar + g*GRP_STR;

    __shared__ _Float16 w_lds[CPB_][WSTR];     // 62208 B
    __shared__ float    nrm_lds[2][KIP0];      //  1792 B

    load_weights(l, colbase, tid, wih0, wihr, whh, rmean, rvar, w_lds, nrm_lds);

    const int wid  = tid >> 6;
    const int lane = tid & 63;
    const int wv   = idx*4 + wid;

    // hidden state for this wave's phase-2 task lives in registers
    float hreg[5] = {0.f, 0.f, 0.f, 0.f, 0.f};
    if (wv < L_*RPG_) {
        const int l2 = wv >> 5, row = wv & 31, b2 = g*RPG_ + row;
#pragma unroll
        for (int i = 0; i < 5; ++i)
            hreg[i] = h0[(size_t)l2*BH_ + (size_t)b2*H_ + lane + i*64];
    }

    for (int tau = 0; tau < T_ + L_ - 1; ++tau) {
        const int t = tau - l;
        if (t >= 0 && t < T_)
            phase1_dispatch(g, l, t, colbase, tid, x, stf, bih, bhh,
                            zbuf, hnbuf, w_lds, nrm_lds);
        group_barrier(cnt, tid, (unsigned)(2*tau + 1));
        phase2_work(g, tau, wv, lane, lng, lnb, hreg, stf, zbuf, hnbuf, out);
        group_barrier(cnt, tid, (unsigned)(2*tau + 2));
    }
}

extern "C" void kernel_launch(void* const* d_in, const int* in_sizes, int n_in,
                              void* d_out, int out_size, void* d_ws, size_t ws_size,
                              hipStream_t stream) {
    (void)in_sizes; (void)n_in; (void)out_size; (void)ws_size;
    const float* x     = (const float*)d_in[0];
    const float* h0    = (const float*)d_in[1];
    const float* rmean = (const float*)d_in[2];
    const float* rvar  = (const float*)d_in[3];
    const float* wih0  = (const float*)d_in[4];
    const float* wihr  = (const float*)d_in[5];
    const float* whh   = (const float*)d_in[6];
    const float* bih   = (const float*)d_in[7];
    const float* bhh   = (const float*)d_in[8];
    const float* lng   = (const float*)d_in[9];
    const float* lnb   = (const float*)d_in[10];
    float* out = (float*)d_out;
    float* ws  = (float*)d_ws;

    // Plain launches only: hipLaunchCooperativeKernel silently rejected the
    // grid in r9/r10 (zeros, healthy stream) while the identical kernel body
    // needs no grid.sync. No runtime queries (capture-sensitive, r4-r8).
    k_init<<<dim3(240), dim3(NTHR), 0, stream>>>(h0, ws);
    gru_pers_kernel<<<dim3(NBLK), dim3(NTHR), 0, stream>>>(
        x, h0, rmean, rvar, wih0, wihr, whh, bih, bhh, lng, lnb, out, ws);
}

// Round 12
// 8923.167 us; speedup vs baseline: 3.1440x; 1.2065x over previous
//
#include <hip/hip_runtime.h>
#include <hip/hip_fp16.h>

#define B_   256
#define T_   512
#define D_   200
#define H_   320
#define L_   3
#define G3_  960
#define BH_  (B_*H_)
#define BTH_ (B_*T_*H_)

#define GR_   8              // groups (batch split)
#define RPG_  32             // rows (batch) per group
#define CPB_  48             // output cols per block
#define NCG_  20             // col-groups per layer (960/48)
#define SPG_  60             // blocks per group (3 layers * 20)
#define NP2_  24             // blocks per group that own phase-2 tasks (96/4)
#define NBLK  480            // 2/CU co-residency proven on HW (r7/r8/r11)
#define NTHR  256
#define KIP0  224            // layer-0 input K padded to 32-multiple
#define WSTR  648            // LDS weight row stride in f16 elems

typedef _Float16 half8 __attribute__((ext_vector_type(8)));
typedef float    f32x4 __attribute__((ext_vector_type(4)));

// ---- ws layout (floats) ----
#define OFF_Z     0
#define SZ_Z      (L_*B_*G3_)
#define OFF_HN    (OFF_Z + SZ_Z)
#define SZ_HN     (L_*B_*H_)
#define OFF_STF   (OFF_HN + SZ_HN)         // f16 hidden state (cross-block, coherent)
#define SZ_STF_F  ((L_*BH_)/2)
#define OFF_BAR   (OFF_STF + SZ_STF_F)
// per group: flags[60] spaced 32 words (128B), epoch at word 1920
#define FLAG_STR  32
#define EPOCH_W   (SPG_*FLAG_STR)          // 1920
#define GRP_STR   2048
#define BAR_WORDS (GR_*GRP_STR)            // 16384

__device__ __forceinline__ float sigmoidf_(float v) {
    return 1.0f / (1.0f + __expf(-v));
}

__device__ __forceinline__ float wredsum(float v) {
#pragma unroll
    for (int m = 32; m > 0; m >>= 1) v += __shfl_xor(v, m, 64);
    return v;
}

__device__ __forceinline__ half8 h8zero() {
    half8 a;
#pragma unroll
    for (int j = 0; j < 8; ++j) a[j] = (_Float16)0.f;
    return a;
}

// relaxed agent-scope (device-coherent, MALL-served) atomic helpers
__device__ __forceinline__ unsigned aload(const unsigned* p) {
    return __hip_atomic_load(p, __ATOMIC_RELAXED, __HIP_MEMORY_SCOPE_AGENT);
}
__device__ __forceinline__ void stc(unsigned* p, unsigned v) {
    __hip_atomic_store(p, v, __ATOMIC_RELAXED, __HIP_MEMORY_SCOPE_AGENT);
}
__device__ __forceinline__ void stcf(float* p, float v) {
    stc((unsigned*)p, __builtin_bit_cast(unsigned, v));
}

// -------- flag-array group barrier (no RMW contention, fence-free) ----------
// Each block owns one flag line; arrival = relaxed store of monotonic token.
// Leader (idx==0) wave-0 scans all 60 flags in parallel, posts monotonic
// epoch; waiters poll epoch. __syncthreads on entry drains vmcnt so all
// coherent data stores are MALL-visible before the flag store issues.
// wait=false: signal only (block has no data dependency on this barrier).
__device__ __forceinline__ void gbar(unsigned* greg, int idx, int tid,
                                     unsigned token, bool wait) {
    __syncthreads();
    if (tid == 0) stc(&greg[idx*FLAG_STR], token);
    if (idx == 0) {
        if (tid < 64) {
            for (;;) {
                unsigned v = (tid < SPG_) ? aload(&greg[tid*FLAG_STR]) : token;
                if (__all((int)(v - token) >= 0)) break;
                __builtin_amdgcn_s_sleep(1);
            }
            if (tid == 0) stc(&greg[EPOCH_W], token);
        }
    } else if (wait && tid == 0) {
        while ((int)(aload(&greg[EPOCH_W]) - token) < 0)
            __builtin_amdgcn_s_sleep(1);
    }
    __syncthreads();
}

__device__ __forceinline__ void load_weights(int l, int colbase, int tid,
        const float* __restrict__ wih0, const float* __restrict__ wihr,
        const float* __restrict__ whh,  const float* __restrict__ rmean,
        const float* __restrict__ rvar,
        _Float16 (*w)[WSTR], float (*nrm)[KIP0])
{
    for (int e = tid; e < CPB_*WSTR; e += NTHR) ((_Float16*)w)[e] = (_Float16)0.f;
    if (l == 0) for (int e = tid; e < 2*KIP0; e += NTHR) ((float*)nrm)[e] = 0.f;
    __syncthreads();
    const int KI  = (l == 0) ? D_ : H_;
    const int KIP = (l == 0) ? KIP0 : H_;
    for (int e = tid; e < CPB_*KI; e += NTHR) {
        int c = e / KI, k = e - c*KI;
        float v = (l == 0) ? wih0[(size_t)(colbase + c)*D_ + k]
                           : wihr[((size_t)(l-1)*G3_ + colbase + c)*H_ + k];
        w[c][k] = (_Float16)v;
    }
    for (int e = tid; e < CPB_*H_; e += NTHR) {
        int c = e / H_, k = e - c*H_;
        w[c][KIP + k] = (_Float16)whh[((size_t)l*G3_ + colbase + c)*H_ + k];
    }
    if (l == 0) {
        for (int k = tid; k < D_; k += NTHR) {
            nrm[0][k] = rmean[k];
            nrm[1][k] = rsqrtf(rvar[k] + 1e-8f);
        }
    }
    __syncthreads();
}

template<int KTI, bool L0>
__device__ __forceinline__ void phase1_work(int g, int l, int t, int colbase, int tid,
        const float* __restrict__ x, const _Float16* __restrict__ stf,
        const float* __restrict__ bih, const float* __restrict__ bhh,
        float* __restrict__ zbuf, float* __restrict__ hnbuf,
        const _Float16 (*w)[WSTR], const float (*nrm)[KIP0])
{
    const int wid  = tid >> 6;       // 0 or 1 (caller gates wid<2)
    const int lane = tid & 63;
    const int nr   = lane & 15;
    const int grp  = lane >> 4;
    const int mb   = g*RPG_ + wid*16;
    constexpr int KIP = KTI * 32;

    half8 aI[KTI];
    f32x4 rI[KTI];
    f32x4 rH[10];

    if (L0) {
        // x is a kernel input (read-only): plain cached loads + normalize+clamp
#pragma unroll
        for (int kt = 0; kt < KTI; ++kt) {
            if (kt == KTI-1 && grp > 0) { aI[kt] = h8zero(); continue; }
            const int k0 = kt*32 + grp*8;
            const float* xr = &x[((size_t)(mb + nr)*T_ + t)*D_ + k0];
            float xv[8];
            *(float4*)&xv[0] = *(const float4*)xr;
            *(float4*)&xv[4] = *(const float4*)(xr + 4);
#pragma unroll
            for (int j = 0; j < 8; ++j) {
                float nv = (xv[j] - nrm[0][k0+j]) * nrm[1][k0+j];
                aI[kt][j] = (_Float16)fminf(fmaxf(nv, -10.f), 10.f);
            }
        }
    } else {
        // cross-block hidden state: batch-issue MALL-coherent 16B loads
        const _Float16* srcI = &stf[(size_t)(l-1)*BH_ + (size_t)(mb + nr)*H_ + grp*8];
#pragma unroll
        for (int kt = 0; kt < KTI; ++kt)
            asm volatile("global_load_dwordx4 %0, %1, off offset:%2 sc0 sc1"
                         : "=&v"(rI[kt]) : "v"(srcI), "i"(kt*64));
    }
    {
        const _Float16* srcH = &stf[(size_t)l*BH_ + (size_t)(mb + nr)*H_ + grp*8];
#pragma unroll
        for (int kt = 0; kt < 10; ++kt)
            asm volatile("global_load_dwordx4 %0, %1, off offset:%2 sc0 sc1"
                         : "=&v"(rH[kt]) : "v"(srcH), "i"(kt*64));
    }
    asm volatile("s_waitcnt vmcnt(0)" ::: "memory");
    __builtin_amdgcn_sched_barrier(0);
    if (!L0) {
#pragma unroll
        for (int kt = 0; kt < KTI; ++kt) aI[kt] = __builtin_bit_cast(half8, rI[kt]);
    }

    f32x4 accI[3], accH[3];
#pragma unroll
    for (int nt = 0; nt < 3; ++nt) {
#pragma unroll
        for (int r = 0; r < 4; ++r) { accI[nt][r] = 0.f; accH[nt][r] = 0.f; }
    }

#pragma unroll
    for (int kt = 0; kt < KTI; ++kt) {
        const int k0 = kt*32 + grp*8;
#pragma unroll
        for (int nt = 0; nt < 3; ++nt) {
            half8 bf = *(const half8*)&w[nt*16 + nr][k0];
            accI[nt] = __builtin_amdgcn_mfma_f32_16x16x32_f16(aI[kt], bf, accI[nt], 0, 0, 0);
        }
    }
#pragma unroll
    for (int kt = 0; kt < 10; ++kt) {
        const int k0 = kt*32 + grp*8;
        half8 ah = __builtin_bit_cast(half8, rH[kt]);
#pragma unroll
        for (int nt = 0; nt < 3; ++nt) {
            half8 bf = *(const half8*)&w[nt*16 + nr][KIP + k0];
            accH[nt] = __builtin_amdgcn_mfma_f32_16x16x32_f16(ah, bf, accH[nt], 0, 0, 0);
        }
    }

    // ---- store pre-activations: coherent (MALL write-through) stores ----
#pragma unroll
    for (int nt = 0; nt < 3; ++nt) {
        const int col = colbase + nt*16 + nr;
        const float bi = bih[l*G3_ + col];
        const float bh = bhh[l*G3_ + col];
        const bool ru = (colbase + nt*16) < 2*H_;
#pragma unroll
        for (int r = 0; r < 4; ++r) {
            const int m = mb + grp*4 + r;
            const size_t zi = ((size_t)l*B_ + m)*G3_ + col;
            if (ru) {
                stcf(&zbuf[zi], accI[nt][r] + accH[nt][r] + bi + bh);
            } else {
                stcf(&zbuf[zi], accI[nt][r] + bi);
                stcf(&hnbuf[((size_t)l*B_ + m)*H_ + (col - 2*H_)], accH[nt][r] + bh);
            }
        }
    }
}

__device__ __forceinline__ void phase1_dispatch(int g, int l, int t, int colbase, int tid,
        const float* x, const _Float16* stf, const float* bih, const float* bhh,
        float* zbuf, float* hnbuf, const _Float16 (*w)[WSTR], const float (*nrm)[KIP0])
{
    if ((tid >> 6) >= 2) return;   // 2 waves of 16 rows cover RPG_=32
    if (l == 0) phase1_work<7,  true >(g, l, t, colbase, tid, x, stf, bih, bhh, zbuf, hnbuf, w, nrm);
    else        phase1_work<10, false>(g, l, t, colbase, tid, x, stf, bih, bhh, zbuf, hnbuf, w, nrm);
}

__device__ __forceinline__ void phase2_work(int g, int tau, int wv, int lane,
        const float* __restrict__ lng, const float* __restrict__ lnb,
        float* hreg, _Float16* __restrict__ stf,
        const float* __restrict__ zbuf, const float* __restrict__ hnbuf,
        float* __restrict__ out)
{
    if (wv >= L_*RPG_) return;            // 96 tasks per group
    const int l2  = wv >> 5;
    const int row = wv & 31;
    const int b2  = g*RPG_ + row;
    const int t2  = tau - l2;
    if (t2 < 0 || t2 >= T_) return;

    const float* zp   = &zbuf[((size_t)l2*B_ + b2)*G3_ + lane];
    const float* hp   = &hnbuf[((size_t)l2*B_ + b2)*H_ + lane];
    _Float16*    frow = &stf[(size_t)l2*BH_ + (size_t)b2*H_];

    // batch-issue all 20 coherent loads (coalesced 256B/instr), one waitcnt
    float zr[5], zu[5], zn[5], hn[5];
#pragma unroll
    for (int i = 0; i < 5; ++i) {
        asm volatile("global_load_dword %0, %1, off offset:%2 sc0 sc1"
                     : "=&v"(zr[i]) : "v"(zp), "i"(i*256));
        asm volatile("global_load_dword %0, %1, off offset:%2 sc0 sc1"
                     : "=&v"(zu[i]) : "v"(zp), "i"(1280 + i*256));
        asm volatile("global_load_dword %0, %1, off offset:%2 sc0 sc1"
                     : "=&v"(zn[i]) : "v"(zp), "i"(2560 + i*256));
        asm volatile("global_load_dword %0, %1, off offset:%2 sc0 sc1"
                     : "=&v"(hn[i]) : "v"(hp), "i"(i*256));
    }
    asm volatile("s_waitcnt vmcnt(0)" ::: "memory");
    __builtin_amdgcn_sched_barrier(0);

    const float inv320 = 1.0f/320.0f;
    float s  = zr[0]+zr[1]+zr[2]+zr[3]+zr[4];
    float mu = wredsum(s) * inv320;
    float vs = 0.f;
#pragma unroll
    for (int i = 0; i < 5; ++i) { float d = zr[i]-mu; vs += d*d; }
    float inv = rsqrtf(wredsum(vs)*inv320 + 1e-5f);
    float r[5];
#pragma unroll
    for (int i = 0; i < 5; ++i) {
        const int j = lane + i*64;
        r[i] = sigmoidf_((zr[i]-mu)*inv * lng[(l2*3+0)*H_ + j] + lnb[(l2*3+0)*H_ + j]);
    }
    s  = zu[0]+zu[1]+zu[2]+zu[3]+zu[4];
    mu = wredsum(s) * inv320;
    vs = 0.f;
#pragma unroll
    for (int i = 0; i < 5; ++i) { float d = zu[i]-mu; vs += d*d; }
    inv = rsqrtf(wredsum(vs)*inv320 + 1e-5f);
    float u[5];
#pragma unroll
    for (int i = 0; i < 5; ++i) {
        const int j = lane + i*64;
        u[i] = sigmoidf_((zu[i]-mu)*inv * lng[(l2*3+1)*H_ + j] + lnb[(l2*3+1)*H_ + j]);
    }
    float z2[5];
#pragma unroll
    for (int i = 0; i < 5; ++i) z2[i] = zn[i] + r[i]*hn[i];
    s  = z2[0]+z2[1]+z2[2]+z2[3]+z2[4];
    mu = wredsum(s) * inv320;
    vs = 0.f;
#pragma unroll
    for (int i = 0; i < 5; ++i) { float d = z2[i]-mu; vs += d*d; }
    inv = rsqrtf(wredsum(vs)*inv320 + 1e-5f);
#pragma unroll
    for (int i = 0; i < 5; ++i) {
        const int j = lane + i*64;
        float nv = tanhf((z2[i]-mu)*inv * lng[(l2*3+2)*H_ + j] + lnb[(l2*3+2)*H_ + j]);
        float hv = (1.0f - u[i])*nv + u[i]*hreg[i];
        hreg[i] = hv;
        // f16 state: pair adjacent lanes -> one coherent 4B store per even lane
        unsigned hb = (unsigned)__builtin_bit_cast(unsigned short, (_Float16)hv);
        unsigned ob = (unsigned)__shfl_xor((int)hb, 1, 64);
        if ((lane & 1) == 0)
            stc(&((unsigned*)frow)[j >> 1], (hb & 0xffffu) | (ob << 16));
        if (l2 == 2)    out[((size_t)b2*T_ + t2)*H_ + j] = hv;   // plain (host-read)
        if (t2 == T_-1) out[(size_t)BTH_ + ((size_t)l2*B_ + b2)*H_ + j] = hv;
    }
}

// ---- init: zero barrier area, init f16 state from h0 ----
__global__ void k_init(const float* __restrict__ h0, float* __restrict__ ws) {
    _Float16*  stf = (_Float16*)(ws + OFF_STF);
    unsigned*  bar = (unsigned*)(ws + OFF_BAR);
    int gt = blockIdx.x*blockDim.x + threadIdx.x;
    for (int i = gt; i < BAR_WORDS; i += gridDim.x*blockDim.x) bar[i] = 0u;
    for (int i = gt; i < L_*BH_; i += gridDim.x*blockDim.x)
        stf[i] = (_Float16)h0[i];
}

// ================= persistent kernel (PLAIN launch, no grid.sync) ===========
__launch_bounds__(NTHR, 2)
__global__ void gru_pers_kernel(const float* __restrict__ x,
                                const float* __restrict__ h0,
                                const float* __restrict__ rmean,
                                const float* __restrict__ rvar,
                                const float* __restrict__ wih0,
                                const float* __restrict__ wihr,
                                const float* __restrict__ whh,
                                const float* __restrict__ bih,
                                const float* __restrict__ bhh,
                                const float* __restrict__ lng,
                                const float* __restrict__ lnb,
                                float* __restrict__ out,
                                float* __restrict__ ws)
{
    float*     zbuf  = ws + OFF_Z;
    float*     hnbuf = ws + OFF_HN;
    _Float16*  stf   = (_Float16*)(ws + OFF_STF);
    unsigned*  bar   = (unsigned*)(ws + OFF_BAR);

    const int tid = threadIdx.x;
    const int bid = blockIdx.x;
    const int g   = bid & (GR_ - 1);     // any fixed mapping works (MALL-based sync)
    const int idx = bid >> 3;            // 0..59 within group
    const int l   = idx / NCG_;
    const int cgp = idx - l*NCG_;
    const int colbase = cgp * CPB_;
    const bool p2blk = (idx < NP2_);     // this block owns phase-2 tasks

    unsigned* greg = bar + g*GRP_STR;

    __shared__ _Float16 w_lds[CPB_][WSTR];     // 62208 B
    __shared__ float    nrm_lds[2][KIP0];      //  1792 B

    load_weights(l, colbase, tid, wih0, wihr, whh, rmean, rvar, w_lds, nrm_lds);

    const int wid  = tid >> 6;
    const int lane = tid & 63;
    const int wv   = idx*4 + wid;

    // hidden state for this wave's phase-2 task lives in registers
    float hreg[5] = {0.f, 0.f, 0.f, 0.f, 0.f};
    if (wv < L_*RPG_) {
        const int l2 = wv >> 5, row = wv & 31, b2 = g*RPG_ + row;
#pragma unroll
        for (int i = 0; i < 5; ++i)
            hreg[i] = h0[(size_t)l2*BH_ + (size_t)b2*H_ + lane + i*64];
    }

    for (int tau = 0; tau < T_ + L_ - 1; ++tau) {
        const int t = tau - l;
        if (t >= 0 && t < T_)
            phase1_dispatch(g, l, t, colbase, tid, x, stf, bih, bhh,
                            zbuf, hnbuf, w_lds, nrm_lds);
        // barrier A: phase1 done. Only phase-2 blocks need to WAIT on it.
        gbar(greg, idx, tid, (unsigned)(2*tau + 1), p2blk);
        if (p2blk)
            phase2_work(g, tau, wv, lane, lng, lnb, hreg, stf, zbuf, hnbuf, out);
        // barrier B: phase2 done (non-p2 blocks signal vacuously). All wait.
        gbar(greg, idx, tid, (unsigned)(2*tau + 2), true);
    }
}

extern "C" void kernel_launch(void* const* d_in, const int* in_sizes, int n_in,
                              void* d_out, int out_size, void* d_ws, size_t ws_size,
                              hipStream_t stream) {
    (void)in_sizes; (void)n_in; (void)out_size; (void)ws_size;
    const float* x     = (const float*)d_in[0];
    const float* h0    = (const float*)d_in[1];
    const float* rmean = (const float*)d_in[2];
    const float* rvar  = (const float*)d_in[3];
    const float* wih0  = (const float*)d_in[4];
    const float* wihr  = (const float*)d_in[5];
    const float* whh   = (const float*)d_in[6];
    const float* bih   = (const float*)d_in[7];
    const float* bhh   = (const float*)d_in[8];
    const float* lng   = (const float*)d_in[9];
    const float* lnb   = (const float*)d_in[10];
    float* out = (float*)d_out;
    float* ws  = (float*)d_ws;

    // Plain launches only (coop rejected in r9/r10); no runtime queries.
    k_init<<<dim3(240), dim3(NTHR), 0, stream>>>(h0, ws);
    gru_pers_kernel<<<dim3(NBLK), dim3(NTHR), 0, stream>>>(
        x, h0, rmean, rvar, wih0, wihr, whh, bih, bhh, lng, lnb, out, ws);
}

// Round 13
// 8808.720 us; speedup vs baseline: 3.1849x; 1.0130x over previous
//
#include <hip/hip_runtime.h>
#include <hip/hip_fp16.h>

#define B_   256
#define T_   512
#define D_   200
#define H_   320
#define L_   3
#define G3_  960
#define BH_  (B_*H_)
#define BTH_ (B_*T_*H_)

#define GR_   8              // groups (batch split)
#define RPG_  32             // rows (batch) per group
#define CPB_  48             // output cols per block
#define NCG_  20             // col-groups per layer (960/48)
#define SPG_  60             // blocks per group (3 layers * 20)
#define NP2_  24             // blocks per group owning phase-2 tasks (96/4)
#define NBLK  480            // 2/CU co-residency proven on HW (r7/r8/r11/r12)
#define NTHR  256
#define KIP0  224            // layer-0 input K padded to 32-multiple
#define WSTR  648            // LDS weight row stride in f16 elems

typedef _Float16 half8 __attribute__((ext_vector_type(8)));
typedef float    f32x4 __attribute__((ext_vector_type(4)));

// ---- ws layout (floats) ----
#define OFF_Z     0
#define SZ_Z      (L_*B_*G3_)
#define OFF_HN    (OFF_Z + SZ_Z)
#define SZ_HN     (L_*B_*H_)
#define OFF_STF   (OFF_HN + SZ_HN)         // f16 hidden state (cross-block, coherent)
#define SZ_STF_F  ((L_*BH_)/2)
#define OFF_BAR   (OFF_STF + SZ_STF_F)
// per group: flagsA[60] @0 (spaced 32 words), flagsB[24] @2048
#define FLAG_STR  32
#define FB_OFF    2048
#define GRP_STR   4096
#define BAR_WORDS (GR_*GRP_STR)            // 32768 u32

__device__ __forceinline__ float sigmoidf_(float v) {
    return 1.0f / (1.0f + __expf(-v));
}

__device__ __forceinline__ float wredsum(float v) {
#pragma unroll
    for (int m = 32; m > 0; m >>= 1) v += __shfl_xor(v, m, 64);
    return v;
}

__device__ __forceinline__ half8 h8zero() {
    half8 a;
#pragma unroll
    for (int j = 0; j < 8; ++j) a[j] = (_Float16)0.f;
    return a;
}

// relaxed agent-scope (device-coherent, MALL-served) atomic helpers
__device__ __forceinline__ unsigned aload(const unsigned* p) {
    return __hip_atomic_load(p, __ATOMIC_RELAXED, __HIP_MEMORY_SCOPE_AGENT);
}
__device__ __forceinline__ void stc(unsigned* p, unsigned v) {
    __hip_atomic_store(p, v, __ATOMIC_RELAXED, __HIP_MEMORY_SCOPE_AGENT);
}
__device__ __forceinline__ void stcf(float* p, float v) {
    stc((unsigned*)p, __builtin_bit_cast(unsigned, v));
}

// -------- leaderless producer/consumer barriers (1 MALL hop each) ----------
// signal: __syncthreads drains vmcnt (all coherent data stores MALL-visible),
// then one relaxed flag store. wait: wave-0 lanes each poll one producer flag
// (parallel), __all ballot; closing __syncthreads releases the block.
__device__ __forceinline__ void bar_signal(unsigned* flags, int idx, int tid,
                                           unsigned token) {
    __syncthreads();
    if (tid == 0) stc(&flags[idx*FLAG_STR], token);
}
__device__ __forceinline__ void bar_wait(unsigned* flags, int nflags, int tid,
                                         unsigned token) {
    if (tid < 64) {
        for (;;) {
            unsigned v = (tid < nflags) ? aload(&flags[tid*FLAG_STR]) : token;
            if (__all((int)(v - token) >= 0)) break;
            __builtin_amdgcn_s_sleep(1);
        }
    }
    __syncthreads();
}

__device__ __forceinline__ void load_weights(int l, int colbase, int tid,
        const float* __restrict__ wih0, const float* __restrict__ wihr,
        const float* __restrict__ whh,  const float* __restrict__ rmean,
        const float* __restrict__ rvar,
        _Float16 (*w)[WSTR], float (*nrm)[KIP0])
{
    for (int e = tid; e < CPB_*WSTR; e += NTHR) ((_Float16*)w)[e] = (_Float16)0.f;
    if (l == 0) for (int e = tid; e < 2*KIP0; e += NTHR) ((float*)nrm)[e] = 0.f;
    __syncthreads();
    const int KI  = (l == 0) ? D_ : H_;
    const int KIP = (l == 0) ? KIP0 : H_;
    for (int e = tid; e < CPB_*KI; e += NTHR) {
        int c = e / KI, k = e - c*KI;
        float v = (l == 0) ? wih0[(size_t)(colbase + c)*D_ + k]
                           : wihr[((size_t)(l-1)*G3_ + colbase + c)*H_ + k];
        w[c][k] = (_Float16)v;
    }
    for (int e = tid; e < CPB_*H_; e += NTHR) {
        int c = e / H_, k = e - c*H_;
        w[c][KIP + k] = (_Float16)whh[((size_t)l*G3_ + colbase + c)*H_ + k];
    }
    if (l == 0) {
        for (int k = tid; k < D_; k += NTHR) {
            nrm[0][k] = rmean[k];
            nrm[1][k] = rsqrtf(rvar[k] + 1e-8f);
        }
    }
    __syncthreads();
}

template<int KTI, bool L0>
__device__ __forceinline__ void phase1_work(int g, int l, int t, int colbase, int tid,
        const float* __restrict__ x, const _Float16* __restrict__ stf,
        const float* __restrict__ bih, const float* __restrict__ bhh,
        float* __restrict__ zbuf, float* __restrict__ hnbuf,
        const _Float16 (*w)[WSTR], const float (*nrm)[KIP0])
{
    const int wid  = tid >> 6;       // 0 or 1 (caller gates wid<2)
    const int lane = tid & 63;
    const int nr   = lane & 15;
    const int grp  = lane >> 4;
    const int mb   = g*RPG_ + wid*16;
    constexpr int KIP = KTI * 32;

    half8 aI[KTI];
    f32x4 rI[KTI];
    f32x4 rH[10];

    if (L0) {
        // x is a kernel input (read-only): plain cached loads + normalize+clamp
#pragma unroll
        for (int kt = 0; kt < KTI; ++kt) {
            if (kt == KTI-1 && grp > 0) { aI[kt] = h8zero(); continue; }
            const int k0 = kt*32 + grp*8;
            const float* xr = &x[((size_t)(mb + nr)*T_ + t)*D_ + k0];
            float xv[8];
            *(float4*)&xv[0] = *(const float4*)xr;
            *(float4*)&xv[4] = *(const float4*)(xr + 4);
#pragma unroll
            for (int j = 0; j < 8; ++j) {
                float nv = (xv[j] - nrm[0][k0+j]) * nrm[1][k0+j];
                aI[kt][j] = (_Float16)fminf(fmaxf(nv, -10.f), 10.f);
            }
        }
    } else {
        // cross-block hidden state: batch-issue MALL-coherent 16B loads
        const _Float16* srcI = &stf[(size_t)(l-1)*BH_ + (size_t)(mb + nr)*H_ + grp*8];
#pragma unroll
        for (int kt = 0; kt < KTI; ++kt)
            asm volatile("global_load_dwordx4 %0, %1, off offset:%2 sc0 sc1"
                         : "=&v"(rI[kt]) : "v"(srcI), "i"(kt*64));
    }
    {
        const _Float16* srcH = &stf[(size_t)l*BH_ + (size_t)(mb + nr)*H_ + grp*8];
#pragma unroll
        for (int kt = 0; kt < 10; ++kt)
            asm volatile("global_load_dwordx4 %0, %1, off offset:%2 sc0 sc1"
                         : "=&v"(rH[kt]) : "v"(srcH), "i"(kt*64));
    }
    asm volatile("s_waitcnt vmcnt(0)" ::: "memory");
    __builtin_amdgcn_sched_barrier(0);
    if (!L0) {
#pragma unroll
        for (int kt = 0; kt < KTI; ++kt) aI[kt] = __builtin_bit_cast(half8, rI[kt]);
    }

    f32x4 accI[3], accH[3];
#pragma unroll
    for (int nt = 0; nt < 3; ++nt) {
#pragma unroll
        for (int r = 0; r < 4; ++r) { accI[nt][r] = 0.f; accH[nt][r] = 0.f; }
    }

#pragma unroll
    for (int kt = 0; kt < KTI; ++kt) {
        const int k0 = kt*32 + grp*8;
#pragma unroll
        for (int nt = 0; nt < 3; ++nt) {
            half8 bf = *(const half8*)&w[nt*16 + nr][k0];
            accI[nt] = __builtin_amdgcn_mfma_f32_16x16x32_f16(aI[kt], bf, accI[nt], 0, 0, 0);
        }
    }
#pragma unroll
    for (int kt = 0; kt < 10; ++kt) {
        const int k0 = kt*32 + grp*8;
        half8 ah = __builtin_bit_cast(half8, rH[kt]);
#pragma unroll
        for (int nt = 0; nt < 3; ++nt) {
            half8 bf = *(const half8*)&w[nt*16 + nr][KIP + k0];
            accH[nt] = __builtin_amdgcn_mfma_f32_16x16x32_f16(ah, bf, accH[nt], 0, 0, 0);
        }
    }

    // ---- store pre-activations: coherent (MALL write-through) stores ----
#pragma unroll
    for (int nt = 0; nt < 3; ++nt) {
        const int col = colbase + nt*16 + nr;
        const float bi = bih[l*G3_ + col];
        const float bh = bhh[l*G3_ + col];
        const bool ru = (colbase + nt*16) < 2*H_;
#pragma unroll
        for (int r = 0; r < 4; ++r) {
            const int m = mb + grp*4 + r;
            const size_t zi = ((size_t)l*B_ + m)*G3_ + col;
            if (ru) {
                stcf(&zbuf[zi], accI[nt][r] + accH[nt][r] + bi + bh);
            } else {
                stcf(&zbuf[zi], accI[nt][r] + bi);
                stcf(&hnbuf[((size_t)l*B_ + m)*H_ + (col - 2*H_)], accH[nt][r] + bh);
            }
        }
    }
}

__device__ __forceinline__ void phase1_dispatch(int g, int l, int t, int colbase, int tid,
        const float* x, const _Float16* stf, const float* bih, const float* bhh,
        float* zbuf, float* hnbuf, const _Float16 (*w)[WSTR], const float (*nrm)[KIP0])
{
    if ((tid >> 6) >= 2) return;   // 2 waves of 16 rows cover RPG_=32
    if (l == 0) phase1_work<7,  true >(g, l, t, colbase, tid, x, stf, bih, bhh, zbuf, hnbuf, w, nrm);
    else        phase1_work<10, false>(g, l, t, colbase, tid, x, stf, bih, bhh, zbuf, hnbuf, w, nrm);
}

__device__ __forceinline__ void phase2_work(int g, int tau, int wv, int lane,
        const float* __restrict__ lng, const float* __restrict__ lnb,
        float* hreg, _Float16* __restrict__ stf,
        const float* __restrict__ zbuf, const float* __restrict__ hnbuf,
        float* __restrict__ out)
{
    if (wv >= L_*RPG_) return;            // 96 tasks per group
    const int l2  = wv >> 5;
    const int row = wv & 31;
    const int b2  = g*RPG_ + row;
    const int t2  = tau - l2;
    if (t2 < 0 || t2 >= T_) return;

    const float* zp   = &zbuf[((size_t)l2*B_ + b2)*G3_ + lane];
    const float* hp   = &hnbuf[((size_t)l2*B_ + b2)*H_ + lane];
    _Float16*    frow = &stf[(size_t)l2*BH_ + (size_t)b2*H_];

    // batch-issue all 20 coherent loads (coalesced 256B/instr), one waitcnt
    float zr[5], zu[5], zn[5], hn[5];
#pragma unroll
    for (int i = 0; i < 5; ++i) {
        asm volatile("global_load_dword %0, %1, off offset:%2 sc0 sc1"
                     : "=&v"(zr[i]) : "v"(zp), "i"(i*256));
        asm volatile("global_load_dword %0, %1, off offset:%2 sc0 sc1"
                     : "=&v"(zu[i]) : "v"(zp), "i"(1280 + i*256));
        asm volatile("global_load_dword %0, %1, off offset:%2 sc0 sc1"
                     : "=&v"(zn[i]) : "v"(zp), "i"(2560 + i*256));
        asm volatile("global_load_dword %0, %1, off offset:%2 sc0 sc1"
                     : "=&v"(hn[i]) : "v"(hp), "i"(i*256));
    }
    asm volatile("s_waitcnt vmcnt(0)" ::: "memory");
    __builtin_amdgcn_sched_barrier(0);

    const float inv320 = 1.0f/320.0f;
    float s  = zr[0]+zr[1]+zr[2]+zr[3]+zr[4];
    float mu = wredsum(s) * inv320;
    float vs = 0.f;
#pragma unroll
    for (int i = 0; i < 5; ++i) { float d = zr[i]-mu; vs += d*d; }
    float inv = rsqrtf(wredsum(vs)*inv320 + 1e-5f);
    float r[5];
#pragma unroll
    for (int i = 0; i < 5; ++i) {
        const int j = lane + i*64;
        r[i] = sigmoidf_((zr[i]-mu)*inv * lng[(l2*3+0)*H_ + j] + lnb[(l2*3+0)*H_ + j]);
    }
    s  = zu[0]+zu[1]+zu[2]+zu[3]+zu[4];
    mu = wredsum(s) * inv320;
    vs = 0.f;
#pragma unroll
    for (int i = 0; i < 5; ++i) { float d = zu[i]-mu; vs += d*d; }
    inv = rsqrtf(wredsum(vs)*inv320 + 1e-5f);
    float u[5];
#pragma unroll
    for (int i = 0; i < 5; ++i) {
        const int j = lane + i*64;
        u[i] = sigmoidf_((zu[i]-mu)*inv * lng[(l2*3+1)*H_ + j] + lnb[(l2*3+1)*H_ + j]);
    }
    float z2[5];
#pragma unroll
    for (int i = 0; i < 5; ++i) z2[i] = zn[i] + r[i]*hn[i];
    s  = z2[0]+z2[1]+z2[2]+z2[3]+z2[4];
    mu = wredsum(s) * inv320;
    vs = 0.f;
#pragma unroll
    for (int i = 0; i < 5; ++i) { float d = z2[i]-mu; vs += d*d; }
    inv = rsqrtf(wredsum(vs)*inv320 + 1e-5f);
#pragma unroll
    for (int i = 0; i < 5; ++i) {
        const int j = lane + i*64;
        float nv = tanhf((z2[i]-mu)*inv * lng[(l2*3+2)*H_ + j] + lnb[(l2*3+2)*H_ + j]);
        float hv = (1.0f - u[i])*nv + u[i]*hreg[i];
        hreg[i] = hv;
        // f16 state: pair adjacent lanes -> one coherent 4B store per even lane
        unsigned hb = (unsigned)__builtin_bit_cast(unsigned short, (_Float16)hv);
        unsigned ob = (unsigned)__shfl_xor((int)hb, 1, 64);
        if ((lane & 1) == 0)
            stc(&((unsigned*)frow)[j >> 1], (hb & 0xffffu) | (ob << 16));
        if (l2 == 2)    out[((size_t)b2*T_ + t2)*H_ + j] = hv;   // plain (host-read)
        if (t2 == T_-1) out[(size_t)BTH_ + ((size_t)l2*B_ + b2)*H_ + j] = hv;
    }
}

// ---- init: zero barrier area, init f16 state from h0 ----
__global__ void k_init(const float* __restrict__ h0, float* __restrict__ ws) {
    _Float16*  stf = (_Float16*)(ws + OFF_STF);
    unsigned*  bar = (unsigned*)(ws + OFF_BAR);
    int gt = blockIdx.x*blockDim.x + threadIdx.x;
    for (int i = gt; i < BAR_WORDS; i += gridDim.x*blockDim.x) bar[i] = 0u;
    for (int i = gt; i < L_*BH_; i += gridDim.x*blockDim.x)
        stf[i] = (_Float16)h0[i];
}

// ================= persistent kernel (PLAIN launch, no grid.sync) ===========
__launch_bounds__(NTHR, 2)
__global__ void gru_pers_kernel(const float* __restrict__ x,
                                const float* __restrict__ h0,
                                const float* __restrict__ rmean,
                                const float* __restrict__ rvar,
                                const float* __restrict__ wih0,
                                const float* __restrict__ wihr,
                                const float* __restrict__ whh,
                                const float* __restrict__ bih,
                                const float* __restrict__ bhh,
                                const float* __restrict__ lng,
                                const float* __restrict__ lnb,
                                float* __restrict__ out,
                                float* __restrict__ ws)
{
    float*     zbuf  = ws + OFF_Z;
    float*     hnbuf = ws + OFF_HN;
    _Float16*  stf   = (_Float16*)(ws + OFF_STF);
    unsigned*  bar   = (unsigned*)(ws + OFF_BAR);

    const int tid = threadIdx.x;
    const int bid = blockIdx.x;
    const int g   = bid & (GR_ - 1);     // any fixed mapping works (MALL-based sync)
    const int idx = bid >> 3;            // 0..59 within group
    const int l   = idx / NCG_;
    const int cgp = idx - l*NCG_;
    const int colbase = cgp * CPB_;
    const bool p2blk = (idx < NP2_);     // this block owns phase-2 tasks

    unsigned* flagsA = bar + g*GRP_STR;
    unsigned* flagsB = bar + g*GRP_STR + FB_OFF;

    __shared__ _Float16 w_lds[CPB_][WSTR];     // 62208 B
    __shared__ float    nrm_lds[2][KIP0];      //  1792 B

    load_weights(l, colbase, tid, wih0, wihr, whh, rmean, rvar, w_lds, nrm_lds);

    const int wid  = tid >> 6;
    const int lane = tid & 63;
    const int wv   = idx*4 + wid;

    // hidden state for this wave's phase-2 task lives in registers
    float hreg[5] = {0.f, 0.f, 0.f, 0.f, 0.f};
    if (wv < L_*RPG_) {
        const int l2 = wv >> 5, row = wv & 31, b2 = g*RPG_ + row;
#pragma unroll
        for (int i = 0; i < 5; ++i)
            hreg[i] = h0[(size_t)l2*BH_ + (size_t)b2*H_ + lane + i*64];
    }

    for (int tau = 0; tau < T_ + L_ - 1; ++tau) {
        const unsigned tok = (unsigned)(tau + 1);
        const int t = tau - l;
        if (t >= 0 && t < T_)
            phase1_dispatch(g, l, t, colbase, tid, x, stf, bih, bhh,
                            zbuf, hnbuf, w_lds, nrm_lds);
        bar_signal(flagsA, idx, tid, tok);          // z of this block is visible
        if (p2blk) {
            bar_wait(flagsA, SPG_, tid, tok);       // all 60 z-producers done
            phase2_work(g, tau, wv, lane, lng, lnb, hreg, stf, zbuf, hnbuf, out);
            bar_signal(flagsB, idx, tid, tok);      // h of this block is visible
        }
        bar_wait(flagsB, NP2_, tid, tok);           // all 24 h-producers done
    }
}

extern "C" void kernel_launch(void* const* d_in, const int* in_sizes, int n_in,
                              void* d_out, int out_size, void* d_ws, size_t ws_size,
                              hipStream_t stream) {
    (void)in_sizes; (void)n_in; (void)out_size; (void)ws_size;
    const float* x     = (const float*)d_in[0];
    const float* h0    = (const float*)d_in[1];
    const float* rmean = (const float*)d_in[2];
    const float* rvar  = (const float*)d_in[3];
    const float* wih0  = (const float*)d_in[4];
    const float* wihr  = (const float*)d_in[5];
    const float* whh   = (const float*)d_in[6];
    const float* bih   = (const float*)d_in[7];
    const float* bhh   = (const float*)d_in[8];
    const float* lng   = (const float*)d_in[9];
    const float* lnb   = (const float*)d_in[10];
    float* out = (float*)d_out;
    float* ws  = (float*)d_ws;

    // Plain launches only (coop rejected in r9/r10); no runtime queries.
    k_init<<<dim3(240), dim3(NTHR), 0, stream>>>(h0, ws);
    gru_pers_kernel<<<dim3(NBLK), dim3(NTHR), 0, stream>>>(
        x, h0, rmean, rvar, wih0, wihr, whh, bih, bhh, lng, lnb, out, ws);
}